// Round 7
// baseline (930.479 us; speedup 1.0000x reference)
//
#include <hip/hip_runtime.h>
#include <hip/hip_bf16.h>

// Problem constants
#define B_  4
#define S_  1024
#define D_  1024
#define H_  16
#define DH_ 64
#define N_  64          // B*H
#define BS_ 4096        // B*S

// Workspace layout (bytes)
#define WS_CUR   0ull                        // 48 MB f32 cur[3][64][1024][64]
#define WS_XH    (WS_CUR + 48ull*1024*1024)  // 8 MB bf16 x_hi [4096][1024]
#define WS_XL    (WS_XH  +  8ull*1024*1024)  // 8 MB bf16 x_lo
#define WS_WCH   (WS_XL  +  8ull*1024*1024)  // 6 MB bf16 WcT_hi [3][1024][1024]
#define WS_WCL   (WS_WCH +  6ull*1024*1024)  // 6 MB bf16 WcT_lo
#define WS_MSK   (WS_WCL +  6ull*1024*1024)  // 1.5 MB masks
// overlays (safe by stream order):
#define WS_CTXH  WS_XH                       // attn output hi (x dead after proj)
#define WS_CTXL  WS_XL
#define WS_WOH   WS_WCH                      // Wo split (WcT dead after proj)
#define WS_WOL   (WS_WCH + 2ull*1024*1024)

typedef __attribute__((ext_vector_type(8))) short short8v;
typedef __attribute__((ext_vector_type(4))) float f32x4;

// round-to-nearest-even bf16 split: x == hi + lo + O(2^-18 |x|)
__device__ inline void bsplit(float x, unsigned short& h, unsigned short& l) {
    unsigned ux = __float_as_uint(x);
    unsigned rh = (ux + 0x7FFFu + ((ux >> 16) & 1u)) >> 16;
    h = (unsigned short)rh;
    float r = x - __uint_as_float(rh << 16);
    unsigned ur = __float_as_uint(r);
    l = (unsigned short)((ur + 0x7FFFu + ((ur >> 16) & 1u)) >> 16);
}

// ---------------------------------------------------------------------------
// x -> bf16 hi/lo split (elementwise)
// ---------------------------------------------------------------------------
__global__ __launch_bounds__(256) void k_split_x(
    const float* __restrict__ x, unsigned short* __restrict__ xh, unsigned short* __restrict__ xl)
{
    int i = (blockIdx.x * 256 + threadIdx.x) * 4;
    float4 v = *reinterpret_cast<const float4*>(&x[i]);
    ushort4 h, l;
    bsplit(v.x, h.x, l.x);
    bsplit(v.y, h.y, l.y);
    bsplit(v.z, h.z, l.z);
    bsplit(v.w, h.w, l.w);
    *reinterpret_cast<ushort4*>(&xh[i]) = h;
    *reinterpret_cast<ushort4*>(&xl[i]) = l;
}

// ---------------------------------------------------------------------------
// Combined projection weights, transposed + split:
// WcT[z][hd][m] = sum_j W_z[h*64+j][m] * Wi_z[d][j]   (hd = h*64+d)
// ---------------------------------------------------------------------------
__global__ __launch_bounds__(256) void k_wc_split(
    const float* __restrict__ Wq, const float* __restrict__ Wk, const float* __restrict__ Wv,
    const float* __restrict__ Wqi, const float* __restrict__ Wki, const float* __restrict__ Wvi,
    unsigned short* __restrict__ wch, unsigned short* __restrict__ wcl)
{
    int z = blockIdx.y, hd = blockIdx.x;
    const float* W  = (z == 0) ? Wq  : (z == 1) ? Wk  : Wv;
    const float* Wi = (z == 0) ? Wqi : (z == 1) ? Wki : Wvi;
    int h = hd >> 6, d = hd & 63;
    int tid = threadIdx.x;

    __shared__ float ws[64];
    if (tid < 64) ws[tid] = Wi[d * 64 + tid];
    __syncthreads();

    const float* Wb = W + (size_t)h * 64 * 1024;
    float acc[4] = {0.f, 0.f, 0.f, 0.f};
    for (int j = 0; j < 64; j++) {
        float wv = ws[j];
        const float* row = Wb + (size_t)j * 1024;
        #pragma unroll
        for (int mi = 0; mi < 4; mi++)
            acc[mi] += row[tid + mi * 256] * wv;
    }
    unsigned short* oh = wch + (size_t)z * 1024 * 1024 + (size_t)hd * 1024;
    unsigned short* ol = wcl + (size_t)z * 1024 * 1024 + (size_t)hd * 1024;
    #pragma unroll
    for (int mi = 0; mi < 4; mi++) {
        unsigned short hh, ll;
        bsplit(acc[mi], hh, ll);
        oh[tid + mi * 256] = hh;
        ol[tid + mi * 256] = ll;
    }
}

// ---------------------------------------------------------------------------
// Wo -> bf16 hi/lo split
// ---------------------------------------------------------------------------
__global__ __launch_bounds__(256) void k_split_wo(
    const float* __restrict__ Wo, unsigned short* __restrict__ wh, unsigned short* __restrict__ wl)
{
    int i = (blockIdx.x * 256 + threadIdx.x) * 4;
    float4 v = *reinterpret_cast<const float4*>(&Wo[i]);
    ushort4 h, l;
    bsplit(v.x, h.x, l.x);
    bsplit(v.y, h.y, l.y);
    bsplit(v.z, h.z, l.z);
    bsplit(v.w, h.w, l.w);
    *reinterpret_cast<ushort4*>(&wh[i]) = h;
    *reinterpret_cast<ushort4*>(&wl[i]) = l;
}

// ---------------------------------------------------------------------------
// Split-bf16 MFMA GEMM: C[m][n] = sum_k A[m][k]*B[n][k]  (B n-major)
// v2: MFMA operands SWAPPED (D is C^T fragment: lane holds m=r15 fixed,
// n = g*4+i contiguous) so the epilogue is pure float4 stores — fixes the
// 8x HBM write amplification of the scalar-scatter epilogue (397MB -> 48MB).
// ---------------------------------------------------------------------------
template<int OUT>
__global__ __launch_bounds__(256, 2) void k_mfma_gemm(
    const unsigned short* __restrict__ Ah, const unsigned short* __restrict__ Al,
    const unsigned short* __restrict__ Bh, const unsigned short* __restrict__ Bl,
    float* __restrict__ C, const float* __restrict__ bias)
{
    __shared__ __align__(16) unsigned short lds[2][4][128 * 40];

    int tid = threadIdx.x;
    int bx = blockIdx.x, by = blockIdx.y, bz = blockIdx.z;
    const unsigned short* Bhz = Bh + (size_t)bz * 1024 * 1024;
    const unsigned short* Blz = Bl + (size_t)bz * 1024 * 1024;
    int rb = bx * 128, cb = by * 128;

    int c0 = tid, c1 = tid + 256;
    int ar0 = c0 >> 2, ak0 = (c0 & 3) * 8;
    int ar1 = c1 >> 2, ak1 = (c1 & 3) * 8;

    uint4 st[8];
    auto issue = [&](int t) {
        int kb = t * 32;
        st[0] = *reinterpret_cast<const uint4*>(&Ah [(size_t)(rb + ar0) * 1024 + kb + ak0]);
        st[1] = *reinterpret_cast<const uint4*>(&Ah [(size_t)(rb + ar1) * 1024 + kb + ak1]);
        st[2] = *reinterpret_cast<const uint4*>(&Al [(size_t)(rb + ar0) * 1024 + kb + ak0]);
        st[3] = *reinterpret_cast<const uint4*>(&Al [(size_t)(rb + ar1) * 1024 + kb + ak1]);
        st[4] = *reinterpret_cast<const uint4*>(&Bhz[(size_t)(cb + ar0) * 1024 + kb + ak0]);
        st[5] = *reinterpret_cast<const uint4*>(&Bhz[(size_t)(cb + ar1) * 1024 + kb + ak1]);
        st[6] = *reinterpret_cast<const uint4*>(&Blz[(size_t)(cb + ar0) * 1024 + kb + ak0]);
        st[7] = *reinterpret_cast<const uint4*>(&Blz[(size_t)(cb + ar1) * 1024 + kb + ak1]);
    };
    auto dswrite = [&](int buf) {
        *reinterpret_cast<uint4*>(&lds[buf][0][ar0 * 40 + ak0]) = st[0];
        *reinterpret_cast<uint4*>(&lds[buf][0][ar1 * 40 + ak1]) = st[1];
        *reinterpret_cast<uint4*>(&lds[buf][1][ar0 * 40 + ak0]) = st[2];
        *reinterpret_cast<uint4*>(&lds[buf][1][ar1 * 40 + ak1]) = st[3];
        *reinterpret_cast<uint4*>(&lds[buf][2][ar0 * 40 + ak0]) = st[4];
        *reinterpret_cast<uint4*>(&lds[buf][2][ar1 * 40 + ak1]) = st[5];
        *reinterpret_cast<uint4*>(&lds[buf][3][ar0 * 40 + ak0]) = st[6];
        *reinterpret_cast<uint4*>(&lds[buf][3][ar1 * 40 + ak1]) = st[7];
    };

    int wid = tid >> 6, lane = tid & 63;
    int wr = wid >> 1, wc = wid & 1;
    int r15 = lane & 15, g = lane >> 4;

    f32x4 acc[4][4];
    #pragma unroll
    for (int mt = 0; mt < 4; mt++)
        #pragma unroll
        for (int nt = 0; nt < 4; nt++)
            acc[mt][nt] = (f32x4){0.f, 0.f, 0.f, 0.f};

    issue(0);
    dswrite(0);
    __syncthreads();

    for (int t = 0; t < 32; t++) {
        if (t < 31) issue(t + 1);
        int buf = t & 1;
        const unsigned short* LAh = lds[buf][0];
        const unsigned short* LAl = lds[buf][1];
        const unsigned short* LBh = lds[buf][2];
        const unsigned short* LBl = lds[buf][3];

        short8v ah[4], al[4], bh[4], bl[4];
        #pragma unroll
        for (int mt = 0; mt < 4; mt++) {
            int ro = (wr * 64 + mt * 16 + r15) * 40 + g * 8;
            ah[mt] = *reinterpret_cast<const short8v*>(&LAh[ro]);
            al[mt] = *reinterpret_cast<const short8v*>(&LAl[ro]);
        }
        #pragma unroll
        for (int nt = 0; nt < 4; nt++) {
            int co = (wc * 64 + nt * 16 + r15) * 40 + g * 8;
            bh[nt] = *reinterpret_cast<const short8v*>(&LBh[co]);
            bl[nt] = *reinterpret_cast<const short8v*>(&LBl[co]);
        }
        // swapped operands: D row <- B(n), D col <- A(m)
        #pragma unroll
        for (int mt = 0; mt < 4; mt++)
            #pragma unroll
            for (int nt = 0; nt < 4; nt++) {
                acc[mt][nt] = __builtin_amdgcn_mfma_f32_16x16x32_bf16(bh[nt], ah[mt], acc[mt][nt], 0, 0, 0);
                acc[mt][nt] = __builtin_amdgcn_mfma_f32_16x16x32_bf16(bl[nt], ah[mt], acc[mt][nt], 0, 0, 0);
                acc[mt][nt] = __builtin_amdgcn_mfma_f32_16x16x32_bf16(bh[nt], al[mt], acc[mt][nt], 0, 0, 0);
            }

        if (t < 31) {
            dswrite((t + 1) & 1);
            __syncthreads();
        }
    }

    if (OUT == 0) {
        float* out = C + (size_t)bz * 64 * 1024 * 64;
        int b = rb >> 10;     // block is fully inside one batch
        #pragma unroll
        for (int nt = 0; nt < 4; nt++) {
            int col = cb + wc * 64 + nt * 16 + g * 4;   // hd base, 16B aligned
            int h = col >> 6, dd = col & 63;
            #pragma unroll
            for (int mt = 0; mt < 4; mt++) {
                int row = rb + wr * 64 + mt * 16 + r15; // b*1024 + s
                int s = row & 1023;
                f32x4 a = acc[mt][nt];
                *reinterpret_cast<float4*>(&out[(((size_t)(b * 16 + h)) * 1024 + s) * 64 + dd]) =
                    make_float4(a[0], a[1], a[2], a[3]);
            }
        }
    } else {
        #pragma unroll
        for (int nt = 0; nt < 4; nt++) {
            int col = cb + wc * 64 + nt * 16 + g * 4;
            float4 bv = *reinterpret_cast<const float4*>(&bias[col]);
            #pragma unroll
            for (int mt = 0; mt < 4; mt++) {
                int row = rb + wr * 64 + mt * 16 + r15;
                f32x4 a = acc[mt][nt];
                *reinterpret_cast<float4*>(&C[(size_t)row * 1024 + col]) =
                    make_float4(a[0] + bv.x, a[1] + bv.y, a[2] + bv.z, a[3] + bv.w);
            }
        }
    }
}

// ---------------------------------------------------------------------------
// Stage B: LIF scan. One wave per (l, n).
// v4: recurrent matvec in REGISTERS. mask is wave-uniform (ballot -> SGPR);
// multiplicand bits become SALU-built {1.0,0.0} scalars feeding v_fma with
// register-resident weights (4 parallel chains). No LDS latency in the serial
// chain. cur staged global->LDS per 64-step batch with counted vmcnt waits.
// ---------------------------------------------------------------------------
__global__ __launch_bounds__(64) void k_lif(
    const float* __restrict__ curAll,
    const float* __restrict__ Wrq, const float* __restrict__ Wrk, const float* __restrict__ Wrv,
    const float* __restrict__ thq, const float* __restrict__ thk, const float* __restrict__ thv,
    unsigned long long* __restrict__ masks)
{
    __shared__ __align__(16) float wlds[64 * 64];      // 16 KB weight stage
    __shared__ __align__(16) float cbuf[2][64 * 64];   // 2 x 16 KB batches

    int bid = blockIdx.x;               // 0..191
    int l = bid >> 6, n = bid & 63;
    const float* W  = (l == 0) ? Wrq : (l == 1) ? Wrk : Wrv;
    const float* th = (l == 0) ? thq : (l == 1) ? thk : thv;
    const float* cbase = curAll + (((size_t)l * 64 + n) * 1024) * 64;
    unsigned long long* mout = masks + ((size_t)l * 64 + n) * 1024;
    int d = threadIdx.x;

    // stage W (16 instrs) then batch 0 (16 instrs)
    #pragma unroll
    for (int j = 0; j < 16; j++)
        __builtin_amdgcn_global_load_lds(
            (const __attribute__((address_space(1))) void*)(W + j * 256 + d * 4),
            (__attribute__((address_space(3))) void*)(&wlds[j * 256]), 16, 0, 0);
    #pragma unroll
    for (int j = 0; j < 16; j++)
        __builtin_amdgcn_global_load_lds(
            (const __attribute__((address_space(1))) void*)(cbase + j * 256 + d * 4),
            (__attribute__((address_space(3))) void*)(&cbuf[0][j * 256]), 16, 0, 0);
    asm volatile("s_waitcnt vmcnt(16)" ::: "memory");   // W resident (batch0 in flight)

    float w[64];
    #pragma unroll
    for (int j4 = 0; j4 < 16; j4++) {
        float4 t = *reinterpret_cast<const float4*>(&wlds[d * 64 + j4 * 4]);
        w[4 * j4 + 0] = t.x; w[4 * j4 + 1] = t.y;
        w[4 * j4 + 2] = t.z; w[4 * j4 + 3] = t.w;
    }
    float theta = th[d];

    float v = 0.f, refrac = 0.f, athr = 1.0f;
    unsigned long long mask = 0ull;
    unsigned bufLo = 0u, bufHi = 0u;

    for (int b = 0; b < 16; b++) {
        if (b < 15) {
            const float* src = cbase + (size_t)(b + 1) * 4096;
            float* dst = cbuf[(b + 1) & 1];
            #pragma unroll
            for (int j = 0; j < 16; j++)
                __builtin_amdgcn_global_load_lds(
                    (const __attribute__((address_space(1))) void*)(src + j * 256 + d * 4),
                    (__attribute__((address_space(3))) void*)(dst + j * 256), 16, 0, 0);
        }
        if (b == 0)      asm volatile("s_waitcnt vmcnt(16)" ::: "memory");
        else if (b < 15) asm volatile("s_waitcnt vmcnt(17)" ::: "memory");
        else             asm volatile("s_waitcnt vmcnt(0)"  ::: "memory");

        const float* cbp = cbuf[b & 1];
        #pragma unroll 2
        for (int i = 0; i < 64; i++) {
            float total = cbp[i * 64 + d];
            if (mask) {                         // wave-uniform skip
                unsigned mlo = __builtin_amdgcn_readfirstlane((unsigned)mask);
                unsigned mhi = __builtin_amdgcn_readfirstlane((unsigned)(mask >> 32));
                float t0 = 0.f, t1 = 0.f, t2 = 0.f, t3 = 0.f;
                #pragma unroll
                for (int j = 0; j < 16; j++) {
                    t0 = fmaf(__uint_as_float(((mlo >> j) & 1u) * 0x3F800000u), w[j], t0);
                    t1 = fmaf(__uint_as_float(((mlo >> (16 + j)) & 1u) * 0x3F800000u), w[16 + j], t1);
                    t2 = fmaf(__uint_as_float(((mhi >> j) & 1u) * 0x3F800000u), w[32 + j], t2);
                    t3 = fmaf(__uint_as_float(((mhi >> (16 + j)) & 1u) * 0x3F800000u), w[48 + j], t3);
                }
                total += (t0 + t1) + (t2 + t3);
            }

            v = 0.9f * v + total;
            v = (refrac <= 0.f) ? v : 0.f;
            bool sp = (v >= athr);
            mask = __ballot(sp);
            bufLo = (d == i) ? (unsigned)mask : bufLo;
            bufHi = (d == i) ? (unsigned)(mask >> 32) : bufHi;
            float sm = sp ? 1.f : 0.f;
            v = sp ? 0.f : v;
            refrac = fmaxf(refrac - 1.f, sm * 2.f);
            athr = 0.95f * athr + sm * theta;
        }
        mout[b * 64 + d] = ((unsigned long long)bufHi << 32) | bufLo;
    }
}

// ---------------------------------------------------------------------------
// Stage C: MFMA attention on spike bitmasks; emits ctx as bf16 hi/lo split.
// ---------------------------------------------------------------------------
#define ATT_C1 0.180336879f    // 0.125 * log2(e)
#define ATT_C2 11.541560327f   // 8 * log2(e)

__device__ inline short8v expand8(unsigned byte) {
    short8v r;
    #pragma unroll
    for (int e = 0; e < 8; e++)
        r[e] = (short)(((byte >> e) & 1u) ? 0x3F80 : 0);
    return r;
}

__device__ inline unsigned bfpk(float x, float y) {
    unsigned ux = __float_as_uint(x);
    unsigned uy = __float_as_uint(y);
    unsigned rx = (ux + 0x7FFFu + ((ux >> 16) & 1u)) >> 16;
    unsigned ry = (uy + 0x7FFFu + ((uy >> 16) & 1u)) >> 16;
    return rx | (ry << 16);
}

__global__ __launch_bounds__(256) void k_attn_mfma(
    const unsigned long long* __restrict__ masks,
    unsigned short* __restrict__ ctxh, unsigned short* __restrict__ ctxl)
{
    __shared__ __align__(16) unsigned short Klds[128][72];
    __shared__ __align__(16) unsigned short Vt[64][136];
    __shared__ unsigned long long vmbuf[2][128];

    const unsigned long long* qm_all = masks;
    const unsigned long long* km_all = masks + (size_t)64 * 1024;
    const unsigned long long* vm_all = masks + (size_t)2 * 64 * 1024;

    int n  = blockIdx.y;
    int qc = blockIdx.x;
    int tid = threadIdx.x;
    int wv = tid >> 6;
    int lane = tid & 63;
    int r15 = lane & 15, g = lane >> 4;

    const unsigned long long* km = km_all + (size_t)n * 1024;
    const unsigned long long* vm = vm_all + (size_t)n * 1024;

    unsigned long long qmask = qm_all[(size_t)n * 1024 + qc * 64 + wv * 16 + r15];
    short8v Qf[2];
    #pragma unroll
    for (int ch = 0; ch < 2; ch++)
        Qf[ch] = expand8((unsigned)(qmask >> ((ch * 4 + g) * 8)) & 0xFFu);

    f32x4 cx[4];
    #pragma unroll
    for (int mt = 0; mt < 4; mt++) cx[mt] = (f32x4){0.f, 0.f, 0.f, 0.f};
    float den = 0.f;

    if (tid < 128) vmbuf[0][tid] = vm[tid];
    __syncthreads();

    for (int kt = 0; kt < 8; kt++) {
        {
            int s = tid >> 1, half = tid & 1;
            unsigned long long m = km[kt * 128 + s];
            #pragma unroll
            for (int j = 0; j < 4; j++) {
                unsigned byte = (unsigned)(m >> (half * 32 + j * 8)) & 0xFFu;
                *reinterpret_cast<short8v*>(&Klds[s][(half * 4 + j) * 8]) = expand8(byte);
            }
        }
        {
            int dh = tid & 63;
            int sc4 = tid >> 6;
            #pragma unroll
            for (int j = 0; j < 4; j++) {
                short8v v2;
                #pragma unroll
                for (int e = 0; e < 8; e++) {
                    unsigned long long mv = vmbuf[kt & 1][sc4 * 32 + j * 8 + e];
                    v2[e] = (short)(((mv >> dh) & 1ull) ? 0x3F80 : 0);
                }
                *reinterpret_cast<short8v*>(&Vt[dh][(sc4 * 4 + j) * 8]) = v2;
            }
        }
        __syncthreads();

        if (tid < 128 && kt + 1 < 8) vmbuf[(kt + 1) & 1][tid] = vm[(kt + 1) * 128 + tid];

        f32x4 pf[8];
        #pragma unroll
        for (int mt = 0; mt < 8; mt++) {
            f32x4 c = (f32x4){0.f, 0.f, 0.f, 0.f};
            #pragma unroll
            for (int ch = 0; ch < 2; ch++) {
                short8v a = *reinterpret_cast<const short8v*>(&Klds[mt * 16 + r15][(ch * 4 + g) * 8]);
                c = __builtin_amdgcn_mfma_f32_16x16x32_bf16(a, Qf[ch], c, 0, 0, 0);
            }
            f32x4 p;
            #pragma unroll
            for (int i = 0; i < 4; i++) {
                p[i] = exp2f(c[i] * ATT_C1 - ATT_C2);
                den += p[i];
            }
            pf[mt] = p;
        }

        int src0 = ((g & 1) << 1) * 16 + r15;
        int src1 = src0 + 16;
        bool hi = (g >= 2);
        #pragma unroll
        for (int c4 = 0; c4 < 4; c4++) {
            unsigned d0 = bfpk(pf[2 * c4][0], pf[2 * c4][1]);
            unsigned d1 = bfpk(pf[2 * c4][2], pf[2 * c4][3]);
            unsigned d2 = bfpk(pf[2 * c4 + 1][0], pf[2 * c4 + 1][1]);
            unsigned d3 = bfpk(pf[2 * c4 + 1][2], pf[2 * c4 + 1][3]);
            unsigned a0 = __shfl((int)d0, src0), b0 = __shfl((int)d2, src0);
            unsigned a1 = __shfl((int)d1, src0), b1 = __shfl((int)d3, src0);
            unsigned a2 = __shfl((int)d0, src1), b2 = __shfl((int)d2, src1);
            unsigned a3 = __shfl((int)d1, src1), b3 = __shfl((int)d3, src1);
            union { unsigned u[4]; short8v s; } bw;
            bw.u[0] = hi ? b0 : a0;
            bw.u[1] = hi ? b1 : a1;
            bw.u[2] = hi ? b2 : a2;
            bw.u[3] = hi ? b3 : a3;
            #pragma unroll
            for (int mt = 0; mt < 4; mt++) {
                short8v a = *reinterpret_cast<const short8v*>(&Vt[mt * 16 + r15][(c4 * 4 + g) * 8]);
                cx[mt] = __builtin_amdgcn_mfma_f32_16x16x32_bf16(a, bw.s, cx[mt], 0, 0, 0);
            }
        }
        __syncthreads();
    }

    den += __shfl_xor(den, 16);
    den += __shfl_xor(den, 32);
    float inv = 1.f / den;

    int b = n >> 4, h = n & 15;
    int row = b * 1024 + qc * 64 + wv * 16 + r15;
    unsigned short* oph = ctxh + (size_t)row * 1024 + h * 64;
    unsigned short* opl = ctxl + (size_t)row * 1024 + h * 64;
    #pragma unroll
    for (int mt = 0; mt < 4; mt++)
        #pragma unroll
        for (int i = 0; i < 4; i++) {
            unsigned short hh, ll;
            bsplit(cx[mt][i] * inv, hh, ll);
            oph[mt * 16 + g * 4 + i] = hh;
            opl[mt * 16 + g * 4 + i] = ll;
        }
}

// ---------------------------------------------------------------------------
extern "C" void kernel_launch(void* const* d_in, const int* in_sizes, int n_in,
                              void* d_out, int out_size, void* d_ws, size_t ws_size,
                              hipStream_t stream) {
    const float* x    = (const float*)d_in[0];
    const float* Wq   = (const float*)d_in[1];
    const float* Wk   = (const float*)d_in[2];
    const float* Wv   = (const float*)d_in[3];
    const float* Wo   = (const float*)d_in[4];
    const float* bo   = (const float*)d_in[5];
    const float* Wqi  = (const float*)d_in[6];
    const float* Wqr  = (const float*)d_in[7];
    const float* Wki  = (const float*)d_in[8];
    const float* Wkr  = (const float*)d_in[9];
    const float* Wvi  = (const float*)d_in[10];
    const float* Wvr  = (const float*)d_in[11];
    const float* thq  = (const float*)d_in[12];
    const float* thk  = (const float*)d_in[13];
    const float* thv  = (const float*)d_in[14];

    char* ws = (char*)d_ws;
    float* cur = (float*)(ws + WS_CUR);
    unsigned short* xh  = (unsigned short*)(ws + WS_XH);
    unsigned short* xl  = (unsigned short*)(ws + WS_XL);
    unsigned short* wch = (unsigned short*)(ws + WS_WCH);
    unsigned short* wcl = (unsigned short*)(ws + WS_WCL);
    unsigned long long* masks = (unsigned long long*)(ws + WS_MSK);
    unsigned short* ctxh = (unsigned short*)(ws + WS_CTXH);
    unsigned short* ctxl = (unsigned short*)(ws + WS_CTXL);
    unsigned short* woh = (unsigned short*)(ws + WS_WOH);
    unsigned short* wol = (unsigned short*)(ws + WS_WOL);
    float* outp = (float*)d_out;

    k_split_x<<<dim3(4096, 1, 1), 256, 0, stream>>>(x, xh, xl);
    k_wc_split<<<dim3(1024, 3, 1), 256, 0, stream>>>(Wq, Wk, Wv, Wqi, Wki, Wvi, wch, wcl);
    k_mfma_gemm<0><<<dim3(32, 8, 3), 256, 0, stream>>>(xh, xl, wch, wcl, cur, nullptr);
    k_split_wo<<<dim3(1024, 1, 1), 256, 0, stream>>>(Wo, woh, wol);
    k_lif<<<dim3(192, 1, 1), 64, 0, stream>>>(cur, Wqr, Wkr, Wvr, thq, thk, thv, masks);
    k_attn_mfma<<<dim3(16, 64, 1), 256, 0, stream>>>(masks, ctxh, ctxl);
    k_mfma_gemm<1><<<dim3(32, 8, 1), 256, 0, stream>>>(ctxh, ctxl, woh, wol, outp, bo);
}

// Round 8
// 631.951 us; speedup vs baseline: 1.4724x; 1.4724x over previous
//
#include <hip/hip_runtime.h>
#include <hip/hip_bf16.h>

// Problem constants
#define B_  4
#define S_  1024
#define D_  1024
#define H_  16
#define DH_ 64
#define N_  64          // B*H
#define BS_ 4096        // B*S

// Workspace layout (bytes)
#define WS_CUR   0ull                        // 48 MB f32 cur[3][64][1024][64]
#define WS_XH    (WS_CUR + 48ull*1024*1024)  // 8 MB bf16 x_hi [4096][1024]
#define WS_XL    (WS_XH  +  8ull*1024*1024)  // 8 MB bf16 x_lo
#define WS_WCH   (WS_XL  +  8ull*1024*1024)  // 6 MB bf16 WcT_hi [3][1024][1024]
#define WS_WCL   (WS_WCH +  6ull*1024*1024)  // 6 MB bf16 WcT_lo
#define WS_MSK   (WS_WCL +  6ull*1024*1024)  // 1.5 MB masks
// overlays (safe by stream order):
#define WS_CTXH  WS_XH                       // attn output hi (x dead after proj)
#define WS_CTXL  WS_XL
#define WS_WOH   WS_WCH                      // Wo split (WcT dead after proj)
#define WS_WOL   (WS_WCH + 2ull*1024*1024)

typedef __attribute__((ext_vector_type(8))) short short8v;
typedef __attribute__((ext_vector_type(4))) float f32x4;

// round-to-nearest-even bf16 split: x == hi + lo + O(2^-18 |x|)
__device__ inline void bsplit(float x, unsigned short& h, unsigned short& l) {
    unsigned ux = __float_as_uint(x);
    unsigned rh = (ux + 0x7FFFu + ((ux >> 16) & 1u)) >> 16;
    h = (unsigned short)rh;
    float r = x - __uint_as_float(rh << 16);
    unsigned ur = __float_as_uint(r);
    l = (unsigned short)((ur + 0x7FFFu + ((ur >> 16) & 1u)) >> 16);
}

// ---------------------------------------------------------------------------
// x -> bf16 hi/lo split (elementwise)
// ---------------------------------------------------------------------------
__global__ __launch_bounds__(256) void k_split_x(
    const float* __restrict__ x, unsigned short* __restrict__ xh, unsigned short* __restrict__ xl)
{
    int i = (blockIdx.x * 256 + threadIdx.x) * 4;
    float4 v = *reinterpret_cast<const float4*>(&x[i]);
    ushort4 h, l;
    bsplit(v.x, h.x, l.x);
    bsplit(v.y, h.y, l.y);
    bsplit(v.z, h.z, l.z);
    bsplit(v.w, h.w, l.w);
    *reinterpret_cast<ushort4*>(&xh[i]) = h;
    *reinterpret_cast<ushort4*>(&xl[i]) = l;
}

// ---------------------------------------------------------------------------
// Combined projection weights, transposed + split:
// WcT[z][hd][m] = sum_j W_z[h*64+j][m] * Wi_z[d][j]   (hd = h*64+d)
// ---------------------------------------------------------------------------
__global__ __launch_bounds__(256) void k_wc_split(
    const float* __restrict__ Wq, const float* __restrict__ Wk, const float* __restrict__ Wv,
    const float* __restrict__ Wqi, const float* __restrict__ Wki, const float* __restrict__ Wvi,
    unsigned short* __restrict__ wch, unsigned short* __restrict__ wcl)
{
    int z = blockIdx.y, hd = blockIdx.x;
    const float* W  = (z == 0) ? Wq  : (z == 1) ? Wk  : Wv;
    const float* Wi = (z == 0) ? Wqi : (z == 1) ? Wki : Wvi;
    int h = hd >> 6, d = hd & 63;
    int tid = threadIdx.x;

    __shared__ float ws[64];
    if (tid < 64) ws[tid] = Wi[d * 64 + tid];
    __syncthreads();

    const float* Wb = W + (size_t)h * 64 * 1024;
    float acc[4] = {0.f, 0.f, 0.f, 0.f};
    for (int j = 0; j < 64; j++) {
        float wv = ws[j];
        const float* row = Wb + (size_t)j * 1024;
        #pragma unroll
        for (int mi = 0; mi < 4; mi++)
            acc[mi] += row[tid + mi * 256] * wv;
    }
    unsigned short* oh = wch + (size_t)z * 1024 * 1024 + (size_t)hd * 1024;
    unsigned short* ol = wcl + (size_t)z * 1024 * 1024 + (size_t)hd * 1024;
    #pragma unroll
    for (int mi = 0; mi < 4; mi++) {
        unsigned short hh, ll;
        bsplit(acc[mi], hh, ll);
        oh[tid + mi * 256] = hh;
        ol[tid + mi * 256] = ll;
    }
}

// ---------------------------------------------------------------------------
// Wo -> bf16 hi/lo split
// ---------------------------------------------------------------------------
__global__ __launch_bounds__(256) void k_split_wo(
    const float* __restrict__ Wo, unsigned short* __restrict__ wh, unsigned short* __restrict__ wl)
{
    int i = (blockIdx.x * 256 + threadIdx.x) * 4;
    float4 v = *reinterpret_cast<const float4*>(&Wo[i]);
    ushort4 h, l;
    bsplit(v.x, h.x, l.x);
    bsplit(v.y, h.y, l.y);
    bsplit(v.z, h.z, l.z);
    bsplit(v.w, h.w, l.w);
    *reinterpret_cast<ushort4*>(&wh[i]) = h;
    *reinterpret_cast<ushort4*>(&wl[i]) = l;
}

// ---------------------------------------------------------------------------
// Split-bf16 MFMA GEMM: C[m][n] = sum_k A[m][k]*B[n][k]  (B n-major)
// v3: distance-2 prefetch. Two register staging sets (stA/stB), loop
// unrolled x2 -> each load set is consumed two compute-blocks after issue
// (~880 cyc window >= HBM latency), compiler emits counted vmcnt(8) waits.
// Swapped MFMA operands (C^T fragment) keep the float4 epilogue.
// ---------------------------------------------------------------------------
template<int OUT>
__global__ __launch_bounds__(256, 2) void k_mfma_gemm(
    const unsigned short* __restrict__ Ah, const unsigned short* __restrict__ Al,
    const unsigned short* __restrict__ Bh, const unsigned short* __restrict__ Bl,
    float* __restrict__ C, const float* __restrict__ bias)
{
    __shared__ __align__(16) unsigned short lds[2][4][128 * 40];

    int tid = threadIdx.x;
    int bx = blockIdx.x, by = blockIdx.y, bz = blockIdx.z;
    const unsigned short* Bhz = Bh + (size_t)bz * 1024 * 1024;
    const unsigned short* Blz = Bl + (size_t)bz * 1024 * 1024;
    int rb = bx * 128, cb = by * 128;

    int c0 = tid, c1 = tid + 256;
    int ar0 = c0 >> 2, ak0 = (c0 & 3) * 8;
    int ar1 = c1 >> 2, ak1 = (c1 & 3) * 8;

    int wid = tid >> 6, lane = tid & 63;
    int wr = wid >> 1, wc = wid & 1;
    int r15 = lane & 15, g = lane >> 4;

    uint4 stA[8], stB[8];

    #define ISSUE(st, t) do {                                                                   \
        int kb = (t) * 32;                                                                      \
        st[0] = *reinterpret_cast<const uint4*>(&Ah [(size_t)(rb + ar0) * 1024 + kb + ak0]);    \
        st[1] = *reinterpret_cast<const uint4*>(&Ah [(size_t)(rb + ar1) * 1024 + kb + ak1]);    \
        st[2] = *reinterpret_cast<const uint4*>(&Al [(size_t)(rb + ar0) * 1024 + kb + ak0]);    \
        st[3] = *reinterpret_cast<const uint4*>(&Al [(size_t)(rb + ar1) * 1024 + kb + ak1]);    \
        st[4] = *reinterpret_cast<const uint4*>(&Bhz[(size_t)(cb + ar0) * 1024 + kb + ak0]);    \
        st[5] = *reinterpret_cast<const uint4*>(&Bhz[(size_t)(cb + ar1) * 1024 + kb + ak1]);    \
        st[6] = *reinterpret_cast<const uint4*>(&Blz[(size_t)(cb + ar0) * 1024 + kb + ak0]);    \
        st[7] = *reinterpret_cast<const uint4*>(&Blz[(size_t)(cb + ar1) * 1024 + kb + ak1]);    \
    } while (0)

    #define DSWRITE(st, buf) do {                                                \
        *reinterpret_cast<uint4*>(&lds[buf][0][ar0 * 40 + ak0]) = st[0];         \
        *reinterpret_cast<uint4*>(&lds[buf][0][ar1 * 40 + ak1]) = st[1];         \
        *reinterpret_cast<uint4*>(&lds[buf][1][ar0 * 40 + ak0]) = st[2];         \
        *reinterpret_cast<uint4*>(&lds[buf][1][ar1 * 40 + ak1]) = st[3];         \
        *reinterpret_cast<uint4*>(&lds[buf][2][ar0 * 40 + ak0]) = st[4];         \
        *reinterpret_cast<uint4*>(&lds[buf][2][ar1 * 40 + ak1]) = st[5];         \
        *reinterpret_cast<uint4*>(&lds[buf][3][ar0 * 40 + ak0]) = st[6];         \
        *reinterpret_cast<uint4*>(&lds[buf][3][ar1 * 40 + ak1]) = st[7];         \
    } while (0)

    f32x4 acc[4][4];
    #pragma unroll
    for (int mt = 0; mt < 4; mt++)
        #pragma unroll
        for (int nt = 0; nt < 4; nt++)
            acc[mt][nt] = (f32x4){0.f, 0.f, 0.f, 0.f};

    auto compute = [&](int buf) {
        const unsigned short* LAh = lds[buf][0];
        const unsigned short* LAl = lds[buf][1];
        const unsigned short* LBh = lds[buf][2];
        const unsigned short* LBl = lds[buf][3];
        short8v ah[4], al[4], bh[4], bl[4];
        #pragma unroll
        for (int mt = 0; mt < 4; mt++) {
            int ro = (wr * 64 + mt * 16 + r15) * 40 + g * 8;
            ah[mt] = *reinterpret_cast<const short8v*>(&LAh[ro]);
            al[mt] = *reinterpret_cast<const short8v*>(&LAl[ro]);
        }
        #pragma unroll
        for (int nt = 0; nt < 4; nt++) {
            int co = (wc * 64 + nt * 16 + r15) * 40 + g * 8;
            bh[nt] = *reinterpret_cast<const short8v*>(&LBh[co]);
            bl[nt] = *reinterpret_cast<const short8v*>(&LBl[co]);
        }
        #pragma unroll
        for (int mt = 0; mt < 4; mt++)
            #pragma unroll
            for (int nt = 0; nt < 4; nt++) {
                acc[mt][nt] = __builtin_amdgcn_mfma_f32_16x16x32_bf16(bh[nt], ah[mt], acc[mt][nt], 0, 0, 0);
                acc[mt][nt] = __builtin_amdgcn_mfma_f32_16x16x32_bf16(bl[nt], ah[mt], acc[mt][nt], 0, 0, 0);
                acc[mt][nt] = __builtin_amdgcn_mfma_f32_16x16x32_bf16(bh[nt], al[mt], acc[mt][nt], 0, 0, 0);
            }
    };

    // prologue: tile 0 -> lds0 (full wait), tile 1 issued into stB
    ISSUE(stA, 0);
    DSWRITE(stA, 0);
    ISSUE(stB, 1);
    __syncthreads();

    #pragma unroll 1
    for (int t = 0; t < 32; t += 2) {
        // even iter: compute lds0; prefetch t+2 into stA; write t+1 (stB) -> lds1
        if (t + 2 < 32) ISSUE(stA, t + 2);
        compute(0);
        if (t + 1 < 32) DSWRITE(stB, 1);
        __syncthreads();
        // odd iter: compute lds1; prefetch t+3 into stB; write t+2 (stA) -> lds0
        if (t + 1 < 32) {
            if (t + 3 < 32) ISSUE(stB, t + 3);
            compute(1);
            if (t + 2 < 32) DSWRITE(stA, 0);
            __syncthreads();
        }
    }
    #undef ISSUE
    #undef DSWRITE

    if (OUT == 0) {
        float* out = C + (size_t)bz * 64 * 1024 * 64;
        int b = rb >> 10;
        #pragma unroll
        for (int nt = 0; nt < 4; nt++) {
            int col = cb + wc * 64 + nt * 16 + g * 4;   // hd base, 16B aligned
            int h = col >> 6, dd = col & 63;
            #pragma unroll
            for (int mt = 0; mt < 4; mt++) {
                int row = rb + wr * 64 + mt * 16 + r15; // b*1024 + s
                int s = row & 1023;
                f32x4 a = acc[mt][nt];
                *reinterpret_cast<float4*>(&out[(((size_t)(b * 16 + h)) * 1024 + s) * 64 + dd]) =
                    make_float4(a[0], a[1], a[2], a[3]);
            }
        }
    } else {
        #pragma unroll
        for (int nt = 0; nt < 4; nt++) {
            int col = cb + wc * 64 + nt * 16 + g * 4;
            float4 bv = *reinterpret_cast<const float4*>(&bias[col]);
            #pragma unroll
            for (int mt = 0; mt < 4; mt++) {
                int row = rb + wr * 64 + mt * 16 + r15;
                f32x4 a = acc[mt][nt];
                *reinterpret_cast<float4*>(&C[(size_t)row * 1024 + col]) =
                    make_float4(a[0] + bv.x, a[1] + bv.y, a[2] + bv.z, a[3] + bv.w);
            }
        }
    }
}

// ---------------------------------------------------------------------------
// Stage B: LIF scan. One wave per (l, n).  (v3 — proven 205 us)
// Nibble-LUT in LDS; cur staged global->LDS in 64-step batches with counted
// vmcnt waits; masks accumulated in regs, one coalesced 8B store per batch.
// ---------------------------------------------------------------------------
__global__ __launch_bounds__(64) void k_lif(
    const float* __restrict__ curAll,
    const float* __restrict__ Wrq, const float* __restrict__ Wrk, const float* __restrict__ Wrv,
    const float* __restrict__ thq, const float* __restrict__ thk, const float* __restrict__ thv,
    unsigned long long* __restrict__ masks)
{
    __shared__ float T[16 * 16 * 64];    // T[g][nib][d], 64 KB
    __shared__ __align__(16) float cbuf[2][64 * 64];   // 2 x 16 KB batch buffers

    int bid = blockIdx.x;               // 0..191
    int l = bid >> 6, n = bid & 63;
    const float* W  = (l == 0) ? Wrq : (l == 1) ? Wrk : Wrv;
    const float* th = (l == 0) ? thq : (l == 1) ? thk : thv;
    const float* cbase = curAll + (((size_t)l * 64 + n) * 1024) * 64;
    unsigned long long* mout = masks + ((size_t)l * 64 + n) * 1024;
    int d = threadIdx.x;

    // issue batch-0 staging first; its latency hides under the table build
    #pragma unroll
    for (int j = 0; j < 16; j++)
        __builtin_amdgcn_global_load_lds(
            (const __attribute__((address_space(1))) void*)(cbase + j * 256 + d * 4),
            (__attribute__((address_space(3))) void*)(&cbuf[0][j * 256]), 16, 0, 0);

    float theta = th[d];

    for (int g = 0; g < 16; g++) {
        float w0 = W[d * 64 + 4 * g + 0];
        float w1 = W[d * 64 + 4 * g + 1];
        float w2 = W[d * 64 + 4 * g + 2];
        float w3 = W[d * 64 + 4 * g + 3];
        #pragma unroll
        for (int c = 0; c < 16; c++) {
            float t = 0.f;
            if (c & 1) t += w0;
            if (c & 2) t += w1;
            if (c & 4) t += w2;
            if (c & 8) t += w3;
            T[g * 1024 + c * 64 + d] = t;
        }
    }
    __syncthreads();   // also drains nothing extra; batch0 still possibly in flight

    float v = 0.f, refrac = 0.f, athr = 1.0f;
    unsigned mlo = 0u, mhi = 0u;
    unsigned bufLo = 0u, bufHi = 0u;

    for (int b = 0; b < 16; b++) {
        if (b < 15) {
            const float* src = cbase + (size_t)(b + 1) * 4096;
            float* dst = cbuf[(b + 1) & 1];
            #pragma unroll
            for (int j = 0; j < 16; j++)
                __builtin_amdgcn_global_load_lds(
                    (const __attribute__((address_space(1))) void*)(src + j * 256 + d * 4),
                    (__attribute__((address_space(3))) void*)(dst + j * 256), 16, 0, 0);
        }
        // steady state outstanding: 16 (batch b+1) + 1 (mask store b-1); drain batch b
        if (b == 0)      asm volatile("s_waitcnt vmcnt(16)" ::: "memory");
        else if (b < 15) asm volatile("s_waitcnt vmcnt(17)" ::: "memory");
        else             asm volatile("s_waitcnt vmcnt(0)"  ::: "memory");

        const float* cb = cbuf[b & 1];
        #pragma unroll 8
        for (int i = 0; i < 64; i++) {
            float curv = cb[i * 64 + d];

            float t[16];
            #pragma unroll
            for (int g = 0; g < 8; g++)
                t[g] = T[g * 1024 + (int)(((mlo >> (4 * g)) & 15u) << 6) + d];
            #pragma unroll
            for (int g = 0; g < 8; g++)
                t[8 + g] = T[(8 + g) * 1024 + (int)(((mhi >> (4 * g)) & 15u) << 6) + d];

            #pragma unroll
            for (int k = 8; k >= 1; k >>= 1)
                #pragma unroll
                for (int j = 0; j < k; j++)
                    t[j] = t[j] + t[j + k];
            float total = curv + t[0];

            v = 0.9f * v + total;
            v = (refrac <= 0.f) ? v : 0.f;
            bool sp = (v >= athr);
            unsigned long long m = __ballot(sp);
            mlo = (unsigned)m;
            mhi = (unsigned)(m >> 32);
            bufLo = (d == i) ? mlo : bufLo;
            bufHi = (d == i) ? mhi : bufHi;
            float sm = sp ? 1.f : 0.f;
            v = sp ? 0.f : v;
            refrac = fmaxf(refrac - 1.f, sm * 2.f);
            athr = 0.95f * athr + sm * theta;
        }
        mout[b * 64 + d] = ((unsigned long long)bufHi << 32) | bufLo;
    }
}

// ---------------------------------------------------------------------------
// Stage C: MFMA attention on spike bitmasks; emits ctx as bf16 hi/lo split.
// ---------------------------------------------------------------------------
#define ATT_C1 0.180336879f    // 0.125 * log2(e)
#define ATT_C2 11.541560327f   // 8 * log2(e)

__device__ inline short8v expand8(unsigned byte) {
    short8v r;
    #pragma unroll
    for (int e = 0; e < 8; e++)
        r[e] = (short)(((byte >> e) & 1u) ? 0x3F80 : 0);
    return r;
}

__device__ inline unsigned bfpk(float x, float y) {
    unsigned ux = __float_as_uint(x);
    unsigned uy = __float_as_uint(y);
    unsigned rx = (ux + 0x7FFFu + ((ux >> 16) & 1u)) >> 16;
    unsigned ry = (uy + 0x7FFFu + ((uy >> 16) & 1u)) >> 16;
    return rx | (ry << 16);
}

__global__ __launch_bounds__(256) void k_attn_mfma(
    const unsigned long long* __restrict__ masks,
    unsigned short* __restrict__ ctxh, unsigned short* __restrict__ ctxl)
{
    __shared__ __align__(16) unsigned short Klds[128][72];
    __shared__ __align__(16) unsigned short Vt[64][136];
    __shared__ unsigned long long vmbuf[2][128];

    const unsigned long long* qm_all = masks;
    const unsigned long long* km_all = masks + (size_t)64 * 1024;
    const unsigned long long* vm_all = masks + (size_t)2 * 64 * 1024;

    int n  = blockIdx.y;
    int qc = blockIdx.x;
    int tid = threadIdx.x;
    int wv = tid >> 6;
    int lane = tid & 63;
    int r15 = lane & 15, g = lane >> 4;

    const unsigned long long* km = km_all + (size_t)n * 1024;
    const unsigned long long* vm = vm_all + (size_t)n * 1024;

    unsigned long long qmask = qm_all[(size_t)n * 1024 + qc * 64 + wv * 16 + r15];
    short8v Qf[2];
    #pragma unroll
    for (int ch = 0; ch < 2; ch++)
        Qf[ch] = expand8((unsigned)(qmask >> ((ch * 4 + g) * 8)) & 0xFFu);

    f32x4 cx[4];
    #pragma unroll
    for (int mt = 0; mt < 4; mt++) cx[mt] = (f32x4){0.f, 0.f, 0.f, 0.f};
    float den = 0.f;

    if (tid < 128) vmbuf[0][tid] = vm[tid];
    __syncthreads();

    for (int kt = 0; kt < 8; kt++) {
        {
            int s = tid >> 1, half = tid & 1;
            unsigned long long m = km[kt * 128 + s];
            #pragma unroll
            for (int j = 0; j < 4; j++) {
                unsigned byte = (unsigned)(m >> (half * 32 + j * 8)) & 0xFFu;
                *reinterpret_cast<short8v*>(&Klds[s][(half * 4 + j) * 8]) = expand8(byte);
            }
        }
        {
            int dh = tid & 63;
            int sc4 = tid >> 6;
            #pragma unroll
            for (int j = 0; j < 4; j++) {
                short8v v2;
                #pragma unroll
                for (int e = 0; e < 8; e++) {
                    unsigned long long mv = vmbuf[kt & 1][sc4 * 32 + j * 8 + e];
                    v2[e] = (short)(((mv >> dh) & 1ull) ? 0x3F80 : 0);
                }
                *reinterpret_cast<short8v*>(&Vt[dh][(sc4 * 4 + j) * 8]) = v2;
            }
        }
        __syncthreads();

        if (tid < 128 && kt + 1 < 8) vmbuf[(kt + 1) & 1][tid] = vm[(kt + 1) * 128 + tid];

        f32x4 pf[8];
        #pragma unroll
        for (int mt = 0; mt < 8; mt++) {
            f32x4 c = (f32x4){0.f, 0.f, 0.f, 0.f};
            #pragma unroll
            for (int ch = 0; ch < 2; ch++) {
                short8v a = *reinterpret_cast<const short8v*>(&Klds[mt * 16 + r15][(ch * 4 + g) * 8]);
                c = __builtin_amdgcn_mfma_f32_16x16x32_bf16(a, Qf[ch], c, 0, 0, 0);
            }
            f32x4 p;
            #pragma unroll
            for (int i = 0; i < 4; i++) {
                p[i] = exp2f(c[i] * ATT_C1 - ATT_C2);
                den += p[i];
            }
            pf[mt] = p;
        }

        int src0 = ((g & 1) << 1) * 16 + r15;
        int src1 = src0 + 16;
        bool hi = (g >= 2);
        #pragma unroll
        for (int c4 = 0; c4 < 4; c4++) {
            unsigned d0 = bfpk(pf[2 * c4][0], pf[2 * c4][1]);
            unsigned d1 = bfpk(pf[2 * c4][2], pf[2 * c4][3]);
            unsigned d2 = bfpk(pf[2 * c4 + 1][0], pf[2 * c4 + 1][1]);
            unsigned d3 = bfpk(pf[2 * c4 + 1][2], pf[2 * c4 + 1][3]);
            unsigned a0 = __shfl((int)d0, src0), b0 = __shfl((int)d2, src0);
            unsigned a1 = __shfl((int)d1, src0), b1 = __shfl((int)d3, src0);
            unsigned a2 = __shfl((int)d0, src1), b2 = __shfl((int)d2, src1);
            unsigned a3 = __shfl((int)d1, src1), b3 = __shfl((int)d3, src1);
            union { unsigned u[4]; short8v s; } bw;
            bw.u[0] = hi ? b0 : a0;
            bw.u[1] = hi ? b1 : a1;
            bw.u[2] = hi ? b2 : a2;
            bw.u[3] = hi ? b3 : a3;
            #pragma unroll
            for (int mt = 0; mt < 4; mt++) {
                short8v a = *reinterpret_cast<const short8v*>(&Vt[mt * 16 + r15][(c4 * 4 + g) * 8]);
                cx[mt] = __builtin_amdgcn_mfma_f32_16x16x32_bf16(a, bw.s, cx[mt], 0, 0, 0);
            }
        }
        __syncthreads();
    }

    den += __shfl_xor(den, 16);
    den += __shfl_xor(den, 32);
    float inv = 1.f / den;

    int b = n >> 4, h = n & 15;
    int row = b * 1024 + qc * 64 + wv * 16 + r15;
    unsigned short* oph = ctxh + (size_t)row * 1024 + h * 64;
    unsigned short* opl = ctxl + (size_t)row * 1024 + h * 64;
    #pragma unroll
    for (int mt = 0; mt < 4; mt++)
        #pragma unroll
        for (int i = 0; i < 4; i++) {
            unsigned short hh, ll;
            bsplit(cx[mt][i] * inv, hh, ll);
            oph[mt * 16 + g * 4 + i] = hh;
            opl[mt * 16 + g * 4 + i] = ll;
        }
}

// ---------------------------------------------------------------------------
extern "C" void kernel_launch(void* const* d_in, const int* in_sizes, int n_in,
                              void* d_out, int out_size, void* d_ws, size_t ws_size,
                              hipStream_t stream) {
    const float* x    = (const float*)d_in[0];
    const float* Wq   = (const float*)d_in[1];
    const float* Wk   = (const float*)d_in[2];
    const float* Wv   = (const float*)d_in[3];
    const float* Wo   = (const float*)d_in[4];
    const float* bo   = (const float*)d_in[5];
    const float* Wqi  = (const float*)d_in[6];
    const float* Wqr  = (const float*)d_in[7];
    const float* Wki  = (const float*)d_in[8];
    const float* Wkr  = (const float*)d_in[9];
    const float* Wvi  = (const float*)d_in[10];
    const float* Wvr  = (const float*)d_in[11];
    const float* thq  = (const float*)d_in[12];
    const float* thk  = (const float*)d_in[13];
    const float* thv  = (const float*)d_in[14];

    char* ws = (char*)d_ws;
    float* cur = (float*)(ws + WS_CUR);
    unsigned short* xh  = (unsigned short*)(ws + WS_XH);
    unsigned short* xl  = (unsigned short*)(ws + WS_XL);
    unsigned short* wch = (unsigned short*)(ws + WS_WCH);
    unsigned short* wcl = (unsigned short*)(ws + WS_WCL);
    unsigned long long* masks = (unsigned long long*)(ws + WS_MSK);
    unsigned short* ctxh = (unsigned short*)(ws + WS_CTXH);
    unsigned short* ctxl = (unsigned short*)(ws + WS_CTXL);
    unsigned short* woh = (unsigned short*)(ws + WS_WOH);
    unsigned short* wol = (unsigned short*)(ws + WS_WOL);
    float* outp = (float*)d_out;

    k_split_x<<<dim3(4096, 1, 1), 256, 0, stream>>>(x, xh, xl);
    k_wc_split<<<dim3(1024, 3, 1), 256, 0, stream>>>(Wq, Wk, Wv, Wqi, Wki, Wvi, wch, wcl);
    k_mfma_gemm<0><<<dim3(32, 8, 3), 256, 0, stream>>>(xh, xl, wch, wcl, cur, nullptr);
    k_split_wo<<<dim3(1024, 1, 1), 256, 0, stream>>>(Wo, woh, wol);
    k_lif<<<dim3(192, 1, 1), 64, 0, stream>>>(cur, Wqr, Wkr, Wvr, thq, thk, thv, masks);
    k_attn_mfma<<<dim3(16, 64, 1), 256, 0, stream>>>(masks, ctxh, ctxl);
    k_mfma_gemm<1><<<dim3(32, 8, 1), 256, 0, stream>>>(ctxh, ctxl, woh, wol, outp, bo);
}

// Round 9
// 601.917 us; speedup vs baseline: 1.5459x; 1.0499x over previous
//
#include <hip/hip_runtime.h>
#include <hip/hip_bf16.h>

// Problem constants
#define B_  4
#define S_  1024
#define D_  1024
#define H_  16
#define DH_ 64
#define N_  64          // B*H
#define BS_ 4096        // B*S

// Workspace layout (bytes)
#define WS_CUR   0ull                        // 48 MB f32 cur[3][64][1024][64]
#define WS_XH    (WS_CUR + 48ull*1024*1024)  // 8 MB bf16 x_hi [4096][1024]
#define WS_XL    (WS_XH  +  8ull*1024*1024)  // 8 MB bf16 x_lo
#define WS_WCH   (WS_XL  +  8ull*1024*1024)  // 6 MB bf16 WcT_hi [3][1024][1024]
#define WS_WCL   (WS_WCH +  6ull*1024*1024)  // 6 MB bf16 WcT_lo
#define WS_MSK   (WS_WCL +  6ull*1024*1024)  // 1.5 MB masks
// overlays (safe by stream order):
#define WS_CTXH  WS_XH                       // attn output hi (x dead after proj)
#define WS_CTXL  WS_XL
#define WS_WOH   WS_WCH                      // Wo split (WcT dead after proj)
#define WS_WOL   (WS_WCH + 2ull*1024*1024)

typedef __attribute__((ext_vector_type(8))) short short8v;
typedef __attribute__((ext_vector_type(4))) float f32x4;

// round-to-nearest-even bf16 split: x == hi + lo + O(2^-18 |x|)
__device__ inline void bsplit(float x, unsigned short& h, unsigned short& l) {
    unsigned ux = __float_as_uint(x);
    unsigned rh = (ux + 0x7FFFu + ((ux >> 16) & 1u)) >> 16;
    h = (unsigned short)rh;
    float r = x - __uint_as_float(rh << 16);
    unsigned ur = __float_as_uint(r);
    l = (unsigned short)((ur + 0x7FFFu + ((ur >> 16) & 1u)) >> 16);
}

// ---------------------------------------------------------------------------
// x -> bf16 hi/lo split (elementwise)
// ---------------------------------------------------------------------------
__global__ __launch_bounds__(256) void k_split_x(
    const float* __restrict__ x, unsigned short* __restrict__ xh, unsigned short* __restrict__ xl)
{
    int i = (blockIdx.x * 256 + threadIdx.x) * 4;
    float4 v = *reinterpret_cast<const float4*>(&x[i]);
    ushort4 h, l;
    bsplit(v.x, h.x, l.x);
    bsplit(v.y, h.y, l.y);
    bsplit(v.z, h.z, l.z);
    bsplit(v.w, h.w, l.w);
    *reinterpret_cast<ushort4*>(&xh[i]) = h;
    *reinterpret_cast<ushort4*>(&xl[i]) = l;
}

// ---------------------------------------------------------------------------
// Combined projection weights, transposed + split:
// WcT[z][hd][m] = sum_j W_z[h*64+j][m] * Wi_z[d][j]   (hd = h*64+d)
// ---------------------------------------------------------------------------
__global__ __launch_bounds__(256) void k_wc_split(
    const float* __restrict__ Wq, const float* __restrict__ Wk, const float* __restrict__ Wv,
    const float* __restrict__ Wqi, const float* __restrict__ Wki, const float* __restrict__ Wvi,
    unsigned short* __restrict__ wch, unsigned short* __restrict__ wcl)
{
    int z = blockIdx.y, hd = blockIdx.x;
    const float* W  = (z == 0) ? Wq  : (z == 1) ? Wk  : Wv;
    const float* Wi = (z == 0) ? Wqi : (z == 1) ? Wki : Wvi;
    int h = hd >> 6, d = hd & 63;
    int tid = threadIdx.x;

    __shared__ float ws[64];
    if (tid < 64) ws[tid] = Wi[d * 64 + tid];
    __syncthreads();

    const float* Wb = W + (size_t)h * 64 * 1024;
    float acc[4] = {0.f, 0.f, 0.f, 0.f};
    for (int j = 0; j < 64; j++) {
        float wv = ws[j];
        const float* row = Wb + (size_t)j * 1024;
        #pragma unroll
        for (int mi = 0; mi < 4; mi++)
            acc[mi] += row[tid + mi * 256] * wv;
    }
    unsigned short* oh = wch + (size_t)z * 1024 * 1024 + (size_t)hd * 1024;
    unsigned short* ol = wcl + (size_t)z * 1024 * 1024 + (size_t)hd * 1024;
    #pragma unroll
    for (int mi = 0; mi < 4; mi++) {
        unsigned short hh, ll;
        bsplit(acc[mi], hh, ll);
        oh[tid + mi * 256] = hh;
        ol[tid + mi * 256] = ll;
    }
}

// ---------------------------------------------------------------------------
// Wo -> bf16 hi/lo split
// ---------------------------------------------------------------------------
__global__ __launch_bounds__(256) void k_split_wo(
    const float* __restrict__ Wo, unsigned short* __restrict__ wh, unsigned short* __restrict__ wl)
{
    int i = (blockIdx.x * 256 + threadIdx.x) * 4;
    float4 v = *reinterpret_cast<const float4*>(&Wo[i]);
    ushort4 h, l;
    bsplit(v.x, h.x, l.x);
    bsplit(v.y, h.y, l.y);
    bsplit(v.z, h.z, l.z);
    bsplit(v.w, h.w, l.w);
    *reinterpret_cast<ushort4*>(&wh[i]) = h;
    *reinterpret_cast<ushort4*>(&wl[i]) = l;
}

// ---------------------------------------------------------------------------
// Split-bf16 MFMA GEMM: C[m][n] = sum_k A[m][k]*B[n][k]  (B n-major)
// v4: 8 waves / 512 threads per 128x128 block -> per-wave tile 64x32.
// Register budget: acc 32 + staging 16 + B-frags 16 + A-frags 8 ~= 95 VGPRs,
// no scratch spills (rounds 5-8 spilled staging: 397-788 MB of HBM traffic).
// launch_bounds(512,2) caps at 256 VGPRs (never forces a spill); actual ~95
// keeps 2 blocks/CU with the 80 KB padded double-buffered LDS.
// Distance-1 prefetch; swapped MFMA operands -> float4 epilogue.
// ---------------------------------------------------------------------------
template<int OUT>
__global__ __launch_bounds__(512, 2) void k_mfma_gemm(
    const unsigned short* __restrict__ Ah, const unsigned short* __restrict__ Al,
    const unsigned short* __restrict__ Bh, const unsigned short* __restrict__ Bl,
    float* __restrict__ C, const float* __restrict__ bias)
{
    __shared__ __align__(16) unsigned short lds[2][4][128 * 40];

    int tid = threadIdx.x;
    int bx = blockIdx.x, by = blockIdx.y, bz = blockIdx.z;
    const unsigned short* Bhz = Bh + (size_t)bz * 1024 * 1024;
    const unsigned short* Blz = Bl + (size_t)bz * 1024 * 1024;
    int rb = bx * 128, cb = by * 128;

    // staging: thread t owns matrix (t>>7) and 4 chunks (t&127)+128i.
    // mat is wave-uniform (t>>7 == wave>>1) -> no divergence.
    int mat = tid >> 7;
    int cch = tid & 127;
    const unsigned short* gsrc = (mat == 0) ? Ah : (mat == 1) ? Al : (mat == 2) ? Bhz : Blz;
    int rowoff = (mat < 2) ? rb : cb;

    uint4 st[4];
    auto issue = [&](int t) {
        int kb = t * 32;
        #pragma unroll
        for (int i = 0; i < 4; i++) {
            int c = cch + 128 * i;
            int row = c >> 2, ko = (c & 3) * 8;
            st[i] = *reinterpret_cast<const uint4*>(&gsrc[(size_t)(rowoff + row) * 1024 + kb + ko]);
        }
    };
    auto dswrite = [&](int buf) {
        #pragma unroll
        for (int i = 0; i < 4; i++) {
            int c = cch + 128 * i;
            int row = c >> 2, ko = (c & 3) * 8;
            *reinterpret_cast<uint4*>(&lds[buf][mat][row * 40 + ko]) = st[i];
        }
    };

    int wid = tid >> 6, lane = tid & 63;
    int wr = wid >> 2, wc = wid & 3;          // 2x4 wave grid: 64-row x 32-col tiles
    int r15 = lane & 15, g = lane >> 4;

    f32x4 acc[4][2];
    #pragma unroll
    for (int mt = 0; mt < 4; mt++)
        #pragma unroll
        for (int nt = 0; nt < 2; nt++)
            acc[mt][nt] = (f32x4){0.f, 0.f, 0.f, 0.f};

    auto compute = [&](int buf) {
        const unsigned short* LAh = lds[buf][0];
        const unsigned short* LAl = lds[buf][1];
        const unsigned short* LBh = lds[buf][2];
        const unsigned short* LBl = lds[buf][3];
        short8v bh[2], bl[2];
        #pragma unroll
        for (int nt = 0; nt < 2; nt++) {
            int co = (wc * 32 + nt * 16 + r15) * 40 + g * 8;
            bh[nt] = *reinterpret_cast<const short8v*>(&LBh[co]);
            bl[nt] = *reinterpret_cast<const short8v*>(&LBl[co]);
        }
        #pragma unroll
        for (int mt = 0; mt < 4; mt++) {
            int ro = (wr * 64 + mt * 16 + r15) * 40 + g * 8;
            short8v ah = *reinterpret_cast<const short8v*>(&LAh[ro]);
            short8v al = *reinterpret_cast<const short8v*>(&LAl[ro]);
            #pragma unroll
            for (int nt = 0; nt < 2; nt++) {
                acc[mt][nt] = __builtin_amdgcn_mfma_f32_16x16x32_bf16(bh[nt], ah, acc[mt][nt], 0, 0, 0);
                acc[mt][nt] = __builtin_amdgcn_mfma_f32_16x16x32_bf16(bl[nt], ah, acc[mt][nt], 0, 0, 0);
                acc[mt][nt] = __builtin_amdgcn_mfma_f32_16x16x32_bf16(bh[nt], al, acc[mt][nt], 0, 0, 0);
            }
        }
    };

    issue(0);
    dswrite(0);
    __syncthreads();

    #pragma unroll 1
    for (int t = 0; t < 32; t++) {
        if (t < 31) issue(t + 1);
        compute(t & 1);
        if (t < 31) {
            dswrite((t + 1) & 1);
            __syncthreads();
        }
    }

    if (OUT == 0) {
        float* out = C + (size_t)bz * 64 * 1024 * 64;
        int b = rb >> 10;
        #pragma unroll
        for (int nt = 0; nt < 2; nt++) {
            int col = cb + wc * 32 + nt * 16 + g * 4;   // hd base, 16B aligned
            int h = col >> 6, dd = col & 63;
            #pragma unroll
            for (int mt = 0; mt < 4; mt++) {
                int row = rb + wr * 64 + mt * 16 + r15; // b*1024 + s
                int s = row & 1023;
                f32x4 a = acc[mt][nt];
                *reinterpret_cast<float4*>(&out[(((size_t)(b * 16 + h)) * 1024 + s) * 64 + dd]) =
                    make_float4(a[0], a[1], a[2], a[3]);
            }
        }
    } else {
        #pragma unroll
        for (int nt = 0; nt < 2; nt++) {
            int col = cb + wc * 32 + nt * 16 + g * 4;
            float4 bv = *reinterpret_cast<const float4*>(&bias[col]);
            #pragma unroll
            for (int mt = 0; mt < 4; mt++) {
                int row = rb + wr * 64 + mt * 16 + r15;
                f32x4 a = acc[mt][nt];
                *reinterpret_cast<float4*>(&C[(size_t)row * 1024 + col]) =
                    make_float4(a[0] + bv.x, a[1] + bv.y, a[2] + bv.z, a[3] + bv.w);
            }
        }
    }
}

// ---------------------------------------------------------------------------
// Stage B: LIF scan. One wave per (l, n).  (v3 — proven 205 us)
// Nibble-LUT in LDS; cur staged global->LDS in 64-step batches with counted
// vmcnt waits; masks accumulated in regs, one coalesced 8B store per batch.
// ---------------------------------------------------------------------------
__global__ __launch_bounds__(64) void k_lif(
    const float* __restrict__ curAll,
    const float* __restrict__ Wrq, const float* __restrict__ Wrk, const float* __restrict__ Wrv,
    const float* __restrict__ thq, const float* __restrict__ thk, const float* __restrict__ thv,
    unsigned long long* __restrict__ masks)
{
    __shared__ float T[16 * 16 * 64];    // T[g][nib][d], 64 KB
    __shared__ __align__(16) float cbuf[2][64 * 64];   // 2 x 16 KB batch buffers

    int bid = blockIdx.x;               // 0..191
    int l = bid >> 6, n = bid & 63;
    const float* W  = (l == 0) ? Wrq : (l == 1) ? Wrk : Wrv;
    const float* th = (l == 0) ? thq : (l == 1) ? thk : thv;
    const float* cbase = curAll + (((size_t)l * 64 + n) * 1024) * 64;
    unsigned long long* mout = masks + ((size_t)l * 64 + n) * 1024;
    int d = threadIdx.x;

    // issue batch-0 staging first; its latency hides under the table build
    #pragma unroll
    for (int j = 0; j < 16; j++)
        __builtin_amdgcn_global_load_lds(
            (const __attribute__((address_space(1))) void*)(cbase + j * 256 + d * 4),
            (__attribute__((address_space(3))) void*)(&cbuf[0][j * 256]), 16, 0, 0);

    float theta = th[d];

    for (int g = 0; g < 16; g++) {
        float w0 = W[d * 64 + 4 * g + 0];
        float w1 = W[d * 64 + 4 * g + 1];
        float w2 = W[d * 64 + 4 * g + 2];
        float w3 = W[d * 64 + 4 * g + 3];
        #pragma unroll
        for (int c = 0; c < 16; c++) {
            float t = 0.f;
            if (c & 1) t += w0;
            if (c & 2) t += w1;
            if (c & 4) t += w2;
            if (c & 8) t += w3;
            T[g * 1024 + c * 64 + d] = t;
        }
    }
    __syncthreads();

    float v = 0.f, refrac = 0.f, athr = 1.0f;
    unsigned mlo = 0u, mhi = 0u;
    unsigned bufLo = 0u, bufHi = 0u;

    for (int b = 0; b < 16; b++) {
        if (b < 15) {
            const float* src = cbase + (size_t)(b + 1) * 4096;
            float* dst = cbuf[(b + 1) & 1];
            #pragma unroll
            for (int j = 0; j < 16; j++)
                __builtin_amdgcn_global_load_lds(
                    (const __attribute__((address_space(1))) void*)(src + j * 256 + d * 4),
                    (__attribute__((address_space(3))) void*)(dst + j * 256), 16, 0, 0);
        }
        // steady state outstanding: 16 (batch b+1) + 1 (mask store b-1); drain batch b
        if (b == 0)      asm volatile("s_waitcnt vmcnt(16)" ::: "memory");
        else if (b < 15) asm volatile("s_waitcnt vmcnt(17)" ::: "memory");
        else             asm volatile("s_waitcnt vmcnt(0)"  ::: "memory");

        const float* cb = cbuf[b & 1];
        #pragma unroll 8
        for (int i = 0; i < 64; i++) {
            float curv = cb[i * 64 + d];

            float t[16];
            #pragma unroll
            for (int g = 0; g < 8; g++)
                t[g] = T[g * 1024 + (int)(((mlo >> (4 * g)) & 15u) << 6) + d];
            #pragma unroll
            for (int g = 0; g < 8; g++)
                t[8 + g] = T[(8 + g) * 1024 + (int)(((mhi >> (4 * g)) & 15u) << 6) + d];

            #pragma unroll
            for (int k = 8; k >= 1; k >>= 1)
                #pragma unroll
                for (int j = 0; j < k; j++)
                    t[j] = t[j] + t[j + k];
            float total = curv + t[0];

            v = 0.9f * v + total;
            v = (refrac <= 0.f) ? v : 0.f;
            bool sp = (v >= athr);
            unsigned long long m = __ballot(sp);
            mlo = (unsigned)m;
            mhi = (unsigned)(m >> 32);
            bufLo = (d == i) ? mlo : bufLo;
            bufHi = (d == i) ? mhi : bufHi;
            float sm = sp ? 1.f : 0.f;
            v = sp ? 0.f : v;
            refrac = fmaxf(refrac - 1.f, sm * 2.f);
            athr = 0.95f * athr + sm * theta;
        }
        mout[b * 64 + d] = ((unsigned long long)bufHi << 32) | bufLo;
    }
}

// ---------------------------------------------------------------------------
// Stage C: MFMA attention on spike bitmasks; emits ctx as bf16 hi/lo split.
// ---------------------------------------------------------------------------
#define ATT_C1 0.180336879f    // 0.125 * log2(e)
#define ATT_C2 11.541560327f   // 8 * log2(e)

__device__ inline short8v expand8(unsigned byte) {
    short8v r;
    #pragma unroll
    for (int e = 0; e < 8; e++)
        r[e] = (short)(((byte >> e) & 1u) ? 0x3F80 : 0);
    return r;
}

__device__ inline unsigned bfpk(float x, float y) {
    unsigned ux = __float_as_uint(x);
    unsigned uy = __float_as_uint(y);
    unsigned rx = (ux + 0x7FFFu + ((ux >> 16) & 1u)) >> 16;
    unsigned ry = (uy + 0x7FFFu + ((uy >> 16) & 1u)) >> 16;
    return rx | (ry << 16);
}

__global__ __launch_bounds__(256) void k_attn_mfma(
    const unsigned long long* __restrict__ masks,
    unsigned short* __restrict__ ctxh, unsigned short* __restrict__ ctxl)
{
    __shared__ __align__(16) unsigned short Klds[128][72];
    __shared__ __align__(16) unsigned short Vt[64][136];
    __shared__ unsigned long long vmbuf[2][128];

    const unsigned long long* qm_all = masks;
    const unsigned long long* km_all = masks + (size_t)64 * 1024;
    const unsigned long long* vm_all = masks + (size_t)2 * 64 * 1024;

    int n  = blockIdx.y;
    int qc = blockIdx.x;
    int tid = threadIdx.x;
    int wv = tid >> 6;
    int lane = tid & 63;
    int r15 = lane & 15, g = lane >> 4;

    const unsigned long long* km = km_all + (size_t)n * 1024;
    const unsigned long long* vm = vm_all + (size_t)n * 1024;

    unsigned long long qmask = qm_all[(size_t)n * 1024 + qc * 64 + wv * 16 + r15];
    short8v Qf[2];
    #pragma unroll
    for (int ch = 0; ch < 2; ch++)
        Qf[ch] = expand8((unsigned)(qmask >> ((ch * 4 + g) * 8)) & 0xFFu);

    f32x4 cx[4];
    #pragma unroll
    for (int mt = 0; mt < 4; mt++) cx[mt] = (f32x4){0.f, 0.f, 0.f, 0.f};
    float den = 0.f;

    if (tid < 128) vmbuf[0][tid] = vm[tid];
    __syncthreads();

    for (int kt = 0; kt < 8; kt++) {
        {
            int s = tid >> 1, half = tid & 1;
            unsigned long long m = km[kt * 128 + s];
            #pragma unroll
            for (int j = 0; j < 4; j++) {
                unsigned byte = (unsigned)(m >> (half * 32 + j * 8)) & 0xFFu;
                *reinterpret_cast<short8v*>(&Klds[s][(half * 4 + j) * 8]) = expand8(byte);
            }
        }
        {
            int dh = tid & 63;
            int sc4 = tid >> 6;
            #pragma unroll
            for (int j = 0; j < 4; j++) {
                short8v v2;
                #pragma unroll
                for (int e = 0; e < 8; e++) {
                    unsigned long long mv = vmbuf[kt & 1][sc4 * 32 + j * 8 + e];
                    v2[e] = (short)(((mv >> dh) & 1ull) ? 0x3F80 : 0);
                }
                *reinterpret_cast<short8v*>(&Vt[dh][(sc4 * 4 + j) * 8]) = v2;
            }
        }
        __syncthreads();

        if (tid < 128 && kt + 1 < 8) vmbuf[(kt + 1) & 1][tid] = vm[(kt + 1) * 128 + tid];

        f32x4 pf[8];
        #pragma unroll
        for (int mt = 0; mt < 8; mt++) {
            f32x4 c = (f32x4){0.f, 0.f, 0.f, 0.f};
            #pragma unroll
            for (int ch = 0; ch < 2; ch++) {
                short8v a = *reinterpret_cast<const short8v*>(&Klds[mt * 16 + r15][(ch * 4 + g) * 8]);
                c = __builtin_amdgcn_mfma_f32_16x16x32_bf16(a, Qf[ch], c, 0, 0, 0);
            }
            f32x4 p;
            #pragma unroll
            for (int i = 0; i < 4; i++) {
                p[i] = exp2f(c[i] * ATT_C1 - ATT_C2);
                den += p[i];
            }
            pf[mt] = p;
        }

        int src0 = ((g & 1) << 1) * 16 + r15;
        int src1 = src0 + 16;
        bool hi = (g >= 2);
        #pragma unroll
        for (int c4 = 0; c4 < 4; c4++) {
            unsigned d0 = bfpk(pf[2 * c4][0], pf[2 * c4][1]);
            unsigned d1 = bfpk(pf[2 * c4][2], pf[2 * c4][3]);
            unsigned d2 = bfpk(pf[2 * c4 + 1][0], pf[2 * c4 + 1][1]);
            unsigned d3 = bfpk(pf[2 * c4 + 1][2], pf[2 * c4 + 1][3]);
            unsigned a0 = __shfl((int)d0, src0), b0 = __shfl((int)d2, src0);
            unsigned a1 = __shfl((int)d1, src0), b1 = __shfl((int)d3, src0);
            unsigned a2 = __shfl((int)d0, src1), b2 = __shfl((int)d2, src1);
            unsigned a3 = __shfl((int)d1, src1), b3 = __shfl((int)d3, src1);
            union { unsigned u[4]; short8v s; } bw;
            bw.u[0] = hi ? b0 : a0;
            bw.u[1] = hi ? b1 : a1;
            bw.u[2] = hi ? b2 : a2;
            bw.u[3] = hi ? b3 : a3;
            #pragma unroll
            for (int mt = 0; mt < 4; mt++) {
                short8v a = *reinterpret_cast<const short8v*>(&Vt[mt * 16 + r15][(c4 * 4 + g) * 8]);
                cx[mt] = __builtin_amdgcn_mfma_f32_16x16x32_bf16(a, bw.s, cx[mt], 0, 0, 0);
            }
        }
        __syncthreads();
    }

    den += __shfl_xor(den, 16);
    den += __shfl_xor(den, 32);
    float inv = 1.f / den;

    int b = n >> 4, h = n & 15;
    int row = b * 1024 + qc * 64 + wv * 16 + r15;
    unsigned short* oph = ctxh + (size_t)row * 1024 + h * 64;
    unsigned short* opl = ctxl + (size_t)row * 1024 + h * 64;
    #pragma unroll
    for (int mt = 0; mt < 4; mt++)
        #pragma unroll
        for (int i = 0; i < 4; i++) {
            unsigned short hh, ll;
            bsplit(cx[mt][i] * inv, hh, ll);
            oph[mt * 16 + g * 4 + i] = hh;
            opl[mt * 16 + g * 4 + i] = ll;
        }
}

// ---------------------------------------------------------------------------
extern "C" void kernel_launch(void* const* d_in, const int* in_sizes, int n_in,
                              void* d_out, int out_size, void* d_ws, size_t ws_size,
                              hipStream_t stream) {
    const float* x    = (const float*)d_in[0];
    const float* Wq   = (const float*)d_in[1];
    const float* Wk   = (const float*)d_in[2];
    const float* Wv   = (const float*)d_in[3];
    const float* Wo   = (const float*)d_in[4];
    const float* bo   = (const float*)d_in[5];
    const float* Wqi  = (const float*)d_in[6];
    const float* Wqr  = (const float*)d_in[7];
    const float* Wki  = (const float*)d_in[8];
    const float* Wkr  = (const float*)d_in[9];
    const float* Wvi  = (const float*)d_in[10];
    const float* Wvr  = (const float*)d_in[11];
    const float* thq  = (const float*)d_in[12];
    const float* thk  = (const float*)d_in[13];
    const float* thv  = (const float*)d_in[14];

    char* ws = (char*)d_ws;
    float* cur = (float*)(ws + WS_CUR);
    unsigned short* xh  = (unsigned short*)(ws + WS_XH);
    unsigned short* xl  = (unsigned short*)(ws + WS_XL);
    unsigned short* wch = (unsigned short*)(ws + WS_WCH);
    unsigned short* wcl = (unsigned short*)(ws + WS_WCL);
    unsigned long long* masks = (unsigned long long*)(ws + WS_MSK);
    unsigned short* ctxh = (unsigned short*)(ws + WS_CTXH);
    unsigned short* ctxl = (unsigned short*)(ws + WS_CTXL);
    unsigned short* woh = (unsigned short*)(ws + WS_WOH);
    unsigned short* wol = (unsigned short*)(ws + WS_WOL);
    float* outp = (float*)d_out;

    k_split_x<<<dim3(4096, 1, 1), 256, 0, stream>>>(x, xh, xl);
    k_wc_split<<<dim3(1024, 3, 1), 256, 0, stream>>>(Wq, Wk, Wv, Wqi, Wki, Wvi, wch, wcl);
    k_mfma_gemm<0><<<dim3(32, 8, 3), 512, 0, stream>>>(xh, xl, wch, wcl, cur, nullptr);
    k_split_wo<<<dim3(1024, 1, 1), 256, 0, stream>>>(Wo, woh, wol);
    k_lif<<<dim3(192, 1, 1), 64, 0, stream>>>(cur, Wqr, Wkr, Wvr, thq, thk, thv, masks);
    k_attn_mfma<<<dim3(16, 64, 1), 256, 0, stream>>>(masks, ctxh, ctxl);
    k_mfma_gemm<1><<<dim3(32, 8, 1), 512, 0, stream>>>(ctxh, ctxl, woh, wol, outp, bo);
}

// Round 10
// 414.565 us; speedup vs baseline: 2.2445x; 1.4519x over previous
//
#include <hip/hip_runtime.h>
#include <hip/hip_bf16.h>

// Problem constants
#define B_  4
#define S_  1024
#define D_  1024
#define H_  16
#define DH_ 64
#define N_  64          // B*H
#define BS_ 4096        // B*S

// Workspace layout (bytes)
#define WS_CUR   0ull                        // 48 MB f32 cur[3][64][1024][64]
#define WS_XH    (WS_CUR + 48ull*1024*1024)  // 8 MB bf16 x_hi [4096][1024]
#define WS_XL    (WS_XH  +  8ull*1024*1024)  // 8 MB bf16 x_lo
#define WS_WCH   (WS_XL  +  8ull*1024*1024)  // 6 MB bf16 WcT_hi [3][1024][1024]
#define WS_WCL   (WS_WCH +  6ull*1024*1024)  // 6 MB bf16 WcT_lo
#define WS_MSK   (WS_WCL +  6ull*1024*1024)  // 1.5 MB masks
// overlays (safe by stream order):
#define WS_CTXH  WS_XH                       // attn output hi (x dead after proj)
#define WS_CTXL  WS_XL
#define WS_WOH   WS_WCH                      // Wo split (WcT dead after proj)
#define WS_WOL   (WS_WCH + 2ull*1024*1024)

typedef __attribute__((ext_vector_type(8))) short short8v;
typedef __attribute__((ext_vector_type(4))) float f32x4;

// round-to-nearest-even bf16 split: x == hi + lo + O(2^-18 |x|)
__device__ inline void bsplit(float x, unsigned short& h, unsigned short& l) {
    unsigned ux = __float_as_uint(x);
    unsigned rh = (ux + 0x7FFFu + ((ux >> 16) & 1u)) >> 16;
    h = (unsigned short)rh;
    float r = x - __uint_as_float(rh << 16);
    unsigned ur = __float_as_uint(r);
    l = (unsigned short)((ur + 0x7FFFu + ((ur >> 16) & 1u)) >> 16);
}

// ---------------------------------------------------------------------------
// x -> bf16 hi/lo split (elementwise)
// ---------------------------------------------------------------------------
__global__ __launch_bounds__(256) void k_split_x(
    const float* __restrict__ x, unsigned short* __restrict__ xh, unsigned short* __restrict__ xl)
{
    int i = (blockIdx.x * 256 + threadIdx.x) * 4;
    float4 v = *reinterpret_cast<const float4*>(&x[i]);
    ushort4 h, l;
    bsplit(v.x, h.x, l.x);
    bsplit(v.y, h.y, l.y);
    bsplit(v.z, h.z, l.z);
    bsplit(v.w, h.w, l.w);
    *reinterpret_cast<ushort4*>(&xh[i]) = h;
    *reinterpret_cast<ushort4*>(&xl[i]) = l;
}

// ---------------------------------------------------------------------------
// Combined projection weights, transposed + split:
// WcT[z][hd][m] = sum_j W_z[h*64+j][m] * Wi_z[d][j]   (hd = h*64+d)
// ---------------------------------------------------------------------------
__global__ __launch_bounds__(256) void k_wc_split(
    const float* __restrict__ Wq, const float* __restrict__ Wk, const float* __restrict__ Wv,
    const float* __restrict__ Wqi, const float* __restrict__ Wki, const float* __restrict__ Wvi,
    unsigned short* __restrict__ wch, unsigned short* __restrict__ wcl)
{
    int z = blockIdx.y, hd = blockIdx.x;
    const float* W  = (z == 0) ? Wq  : (z == 1) ? Wk  : Wv;
    const float* Wi = (z == 0) ? Wqi : (z == 1) ? Wki : Wvi;
    int h = hd >> 6, d = hd & 63;
    int tid = threadIdx.x;

    __shared__ float ws[64];
    if (tid < 64) ws[tid] = Wi[d * 64 + tid];
    __syncthreads();

    const float* Wb = W + (size_t)h * 64 * 1024;
    float acc[4] = {0.f, 0.f, 0.f, 0.f};
    for (int j = 0; j < 64; j++) {
        float wv = ws[j];
        const float* row = Wb + (size_t)j * 1024;
        #pragma unroll
        for (int mi = 0; mi < 4; mi++)
            acc[mi] += row[tid + mi * 256] * wv;
    }
    unsigned short* oh = wch + (size_t)z * 1024 * 1024 + (size_t)hd * 1024;
    unsigned short* ol = wcl + (size_t)z * 1024 * 1024 + (size_t)hd * 1024;
    #pragma unroll
    for (int mi = 0; mi < 4; mi++) {
        unsigned short hh, ll;
        bsplit(acc[mi], hh, ll);
        oh[tid + mi * 256] = hh;
        ol[tid + mi * 256] = ll;
    }
}

// ---------------------------------------------------------------------------
// Wo -> bf16 hi/lo split
// ---------------------------------------------------------------------------
__global__ __launch_bounds__(256) void k_split_wo(
    const float* __restrict__ Wo, unsigned short* __restrict__ wh, unsigned short* __restrict__ wl)
{
    int i = (blockIdx.x * 256 + threadIdx.x) * 4;
    float4 v = *reinterpret_cast<const float4*>(&Wo[i]);
    ushort4 h, l;
    bsplit(v.x, h.x, l.x);
    bsplit(v.y, h.y, l.y);
    bsplit(v.z, h.z, l.z);
    bsplit(v.w, h.w, l.w);
    *reinterpret_cast<ushort4*>(&wh[i]) = h;
    *reinterpret_cast<ushort4*>(&wl[i]) = l;
}

// ---------------------------------------------------------------------------
// Split-bf16 MFMA GEMM: C[m][n] = sum_k A[m][k]*B[n][k]  (B n-major)
// v5: global_load_lds staging — NO staging registers (rounds 5-9 spilled them
// to scratch: 397-788 MB of HBM traffic). BK=64, single 64 KB buffer
// (4 mats x [128 rows][64 bf16] linear), 2 blocks/CU, 2 barriers/K-step;
// cross-block TLP hides HBM latency (m97 mechanism).
// Bank conflicts: XOR-swizzled GLOBAL source (kpos = pos ^ (row&7), an
// involution) + same XOR on ds_read -> 2-way aliasing only (free).
// Swapped MFMA operands -> float4 epilogue. Accumulation order identical.
// ---------------------------------------------------------------------------
template<int OUT>
__global__ __launch_bounds__(512, 4) void k_mfma_gemm(
    const unsigned short* __restrict__ Ah, const unsigned short* __restrict__ Al,
    const unsigned short* __restrict__ Bh, const unsigned short* __restrict__ Bl,
    float* __restrict__ C, const float* __restrict__ bias)
{
    // 4 mats x 128 rows x 64 ushorts = 64 KB. mat m at m*8192 (ushorts).
    __shared__ __align__(16) unsigned short lds[4 * 128 * 64];

    int tid = threadIdx.x;
    int bx = blockIdx.x, by = blockIdx.y, bz = blockIdx.z;
    const unsigned short* Bhz = Bh + (size_t)bz * 1024 * 1024;
    const unsigned short* Blz = Bl + (size_t)bz * 1024 * 1024;
    int rb = bx * 128, cb = by * 128;

    int wid = tid >> 6, lane = tid & 63;
    int wr = wid >> 2, wc = wid & 3;          // 2x4 wave grid: 64-row x 32-col tiles
    int r15 = lane & 15, g = lane >> 4;

    // staging: instr q = wid*8+i -> mat q>>4, 1KB chunk q&15 (8 rows of 128B).
    // lane l: row_in_chunk = l>>3, pos = l&7; global k-pos = pos ^ (l>>3).
    // LDS dest is wave-uniform chunk base (+ lane*16 by hardware).
    int rowA = lane >> 3;          // 0..7, == row&7 within chunk
    int kpsw = ((lane & 7) ^ rowA) * 8;

    f32x4 acc[4][2];
    #pragma unroll
    for (int mt = 0; mt < 4; mt++)
        #pragma unroll
        for (int nt = 0; nt < 2; nt++)
            acc[mt][nt] = (f32x4){0.f, 0.f, 0.f, 0.f};

    #pragma unroll 1
    for (int t = 0; t < 16; t++) {
        int kb = t * 64;
        #pragma unroll
        for (int i = 0; i < 8; i++) {
            int q = wid * 8 + i;
            int mat = q >> 4, ch = q & 15;
            const unsigned short* gsrc = (mat == 0) ? Ah : (mat == 1) ? Al
                                        : (mat == 2) ? Bhz : Blz;
            int rowoff = (mat < 2) ? rb : cb;
            int row = ch * 8 + rowA;
            __builtin_amdgcn_global_load_lds(
                (const __attribute__((address_space(1))) void*)
                    (gsrc + (size_t)(rowoff + row) * 1024 + kb + kpsw),
                (__attribute__((address_space(3))) void*)(&lds[mat * 8192 + ch * 512]),
                16, 0, 0);
        }
        __syncthreads();   // drains vmcnt -> tile resident

        #pragma unroll
        for (int kk = 0; kk < 2; kk++) {
            short8v bh[2], bl[2];
            #pragma unroll
            for (int nt = 0; nt < 2; nt++) {
                int Crow = wc * 32 + nt * 16 + r15;
                int off = Crow * 64 + (((kk * 4 + g) ^ (Crow & 7)) * 8);
                bh[nt] = *reinterpret_cast<const short8v*>(&lds[2 * 8192 + off]);
                bl[nt] = *reinterpret_cast<const short8v*>(&lds[3 * 8192 + off]);
            }
            #pragma unroll
            for (int mt = 0; mt < 4; mt++) {
                int Arow = wr * 64 + mt * 16 + r15;
                int off = Arow * 64 + (((kk * 4 + g) ^ (Arow & 7)) * 8);
                short8v ah = *reinterpret_cast<const short8v*>(&lds[0 * 8192 + off]);
                short8v al = *reinterpret_cast<const short8v*>(&lds[1 * 8192 + off]);
                #pragma unroll
                for (int nt = 0; nt < 2; nt++) {
                    acc[mt][nt] = __builtin_amdgcn_mfma_f32_16x16x32_bf16(bh[nt], ah, acc[mt][nt], 0, 0, 0);
                    acc[mt][nt] = __builtin_amdgcn_mfma_f32_16x16x32_bf16(bl[nt], ah, acc[mt][nt], 0, 0, 0);
                    acc[mt][nt] = __builtin_amdgcn_mfma_f32_16x16x32_bf16(bh[nt], al, acc[mt][nt], 0, 0, 0);
                }
            }
        }
        __syncthreads();   // all waves done reading before next stage overwrites
    }

    if (OUT == 0) {
        float* out = C + (size_t)bz * 64 * 1024 * 64;
        int b = rb >> 10;
        #pragma unroll
        for (int nt = 0; nt < 2; nt++) {
            int col = cb + wc * 32 + nt * 16 + g * 4;   // hd base, 16B aligned
            int h = col >> 6, dd = col & 63;
            #pragma unroll
            for (int mt = 0; mt < 4; mt++) {
                int row = rb + wr * 64 + mt * 16 + r15; // b*1024 + s
                int s = row & 1023;
                f32x4 a = acc[mt][nt];
                *reinterpret_cast<float4*>(&out[(((size_t)(b * 16 + h)) * 1024 + s) * 64 + dd]) =
                    make_float4(a[0], a[1], a[2], a[3]);
            }
        }
    } else {
        #pragma unroll
        for (int nt = 0; nt < 2; nt++) {
            int col = cb + wc * 32 + nt * 16 + g * 4;
            float4 bv = *reinterpret_cast<const float4*>(&bias[col]);
            #pragma unroll
            for (int mt = 0; mt < 4; mt++) {
                int row = rb + wr * 64 + mt * 16 + r15;
                f32x4 a = acc[mt][nt];
                *reinterpret_cast<float4*>(&C[(size_t)row * 1024 + col]) =
                    make_float4(a[0] + bv.x, a[1] + bv.y, a[2] + bv.z, a[3] + bv.w);
            }
        }
    }
}

// ---------------------------------------------------------------------------
// Stage B: LIF scan. One wave per (l, n).  (v3 — proven 205 us)
// Nibble-LUT in LDS; cur staged global->LDS in 64-step batches with counted
// vmcnt waits; masks accumulated in regs, one coalesced 8B store per batch.
// ---------------------------------------------------------------------------
__global__ __launch_bounds__(64) void k_lif(
    const float* __restrict__ curAll,
    const float* __restrict__ Wrq, const float* __restrict__ Wrk, const float* __restrict__ Wrv,
    const float* __restrict__ thq, const float* __restrict__ thk, const float* __restrict__ thv,
    unsigned long long* __restrict__ masks)
{
    __shared__ float T[16 * 16 * 64];    // T[g][nib][d], 64 KB
    __shared__ __align__(16) float cbuf[2][64 * 64];   // 2 x 16 KB batch buffers

    int bid = blockIdx.x;               // 0..191
    int l = bid >> 6, n = bid & 63;
    const float* W  = (l == 0) ? Wrq : (l == 1) ? Wrk : Wrv;
    const float* th = (l == 0) ? thq : (l == 1) ? thk : thv;
    const float* cbase = curAll + (((size_t)l * 64 + n) * 1024) * 64;
    unsigned long long* mout = masks + ((size_t)l * 64 + n) * 1024;
    int d = threadIdx.x;

    // issue batch-0 staging first; its latency hides under the table build
    #pragma unroll
    for (int j = 0; j < 16; j++)
        __builtin_amdgcn_global_load_lds(
            (const __attribute__((address_space(1))) void*)(cbase + j * 256 + d * 4),
            (__attribute__((address_space(3))) void*)(&cbuf[0][j * 256]), 16, 0, 0);

    float theta = th[d];

    for (int g = 0; g < 16; g++) {
        float w0 = W[d * 64 + 4 * g + 0];
        float w1 = W[d * 64 + 4 * g + 1];
        float w2 = W[d * 64 + 4 * g + 2];
        float w3 = W[d * 64 + 4 * g + 3];
        #pragma unroll
        for (int c = 0; c < 16; c++) {
            float t = 0.f;
            if (c & 1) t += w0;
            if (c & 2) t += w1;
            if (c & 4) t += w2;
            if (c & 8) t += w3;
            T[g * 1024 + c * 64 + d] = t;
        }
    }
    __syncthreads();

    float v = 0.f, refrac = 0.f, athr = 1.0f;
    unsigned mlo = 0u, mhi = 0u;
    unsigned bufLo = 0u, bufHi = 0u;

    for (int b = 0; b < 16; b++) {
        if (b < 15) {
            const float* src = cbase + (size_t)(b + 1) * 4096;
            float* dst = cbuf[(b + 1) & 1];
            #pragma unroll
            for (int j = 0; j < 16; j++)
                __builtin_amdgcn_global_load_lds(
                    (const __attribute__((address_space(1))) void*)(src + j * 256 + d * 4),
                    (__attribute__((address_space(3))) void*)(dst + j * 256), 16, 0, 0);
        }
        // steady state outstanding: 16 (batch b+1) + 1 (mask store b-1); drain batch b
        if (b == 0)      asm volatile("s_waitcnt vmcnt(16)" ::: "memory");
        else if (b < 15) asm volatile("s_waitcnt vmcnt(17)" ::: "memory");
        else             asm volatile("s_waitcnt vmcnt(0)"  ::: "memory");

        const float* cb = cbuf[b & 1];
        #pragma unroll 8
        for (int i = 0; i < 64; i++) {
            float curv = cb[i * 64 + d];

            float t[16];
            #pragma unroll
            for (int g = 0; g < 8; g++)
                t[g] = T[g * 1024 + (int)(((mlo >> (4 * g)) & 15u) << 6) + d];
            #pragma unroll
            for (int g = 0; g < 8; g++)
                t[8 + g] = T[(8 + g) * 1024 + (int)(((mhi >> (4 * g)) & 15u) << 6) + d];

            #pragma unroll
            for (int k = 8; k >= 1; k >>= 1)
                #pragma unroll
                for (int j = 0; j < k; j++)
                    t[j] = t[j] + t[j + k];
            float total = curv + t[0];

            v = 0.9f * v + total;
            v = (refrac <= 0.f) ? v : 0.f;
            bool sp = (v >= athr);
            unsigned long long m = __ballot(sp);
            mlo = (unsigned)m;
            mhi = (unsigned)(m >> 32);
            bufLo = (d == i) ? mlo : bufLo;
            bufHi = (d == i) ? mhi : bufHi;
            float sm = sp ? 1.f : 0.f;
            v = sp ? 0.f : v;
            refrac = fmaxf(refrac - 1.f, sm * 2.f);
            athr = 0.95f * athr + sm * theta;
        }
        mout[b * 64 + d] = ((unsigned long long)bufHi << 32) | bufLo;
    }
}

// ---------------------------------------------------------------------------
// Stage C: MFMA attention on spike bitmasks; emits ctx as bf16 hi/lo split.
// ---------------------------------------------------------------------------
#define ATT_C1 0.180336879f    // 0.125 * log2(e)
#define ATT_C2 11.541560327f   // 8 * log2(e)

__device__ inline short8v expand8(unsigned byte) {
    short8v r;
    #pragma unroll
    for (int e = 0; e < 8; e++)
        r[e] = (short)(((byte >> e) & 1u) ? 0x3F80 : 0);
    return r;
}

__device__ inline unsigned bfpk(float x, float y) {
    unsigned ux = __float_as_uint(x);
    unsigned uy = __float_as_uint(y);
    unsigned rx = (ux + 0x7FFFu + ((ux >> 16) & 1u)) >> 16;
    unsigned ry = (uy + 0x7FFFu + ((uy >> 16) & 1u)) >> 16;
    return rx | (ry << 16);
}

__global__ __launch_bounds__(256) void k_attn_mfma(
    const unsigned long long* __restrict__ masks,
    unsigned short* __restrict__ ctxh, unsigned short* __restrict__ ctxl)
{
    __shared__ __align__(16) unsigned short Klds[128][72];
    __shared__ __align__(16) unsigned short Vt[64][136];
    __shared__ unsigned long long vmbuf[2][128];

    const unsigned long long* qm_all = masks;
    const unsigned long long* km_all = masks + (size_t)64 * 1024;
    const unsigned long long* vm_all = masks + (size_t)2 * 64 * 1024;

    int n  = blockIdx.y;
    int qc = blockIdx.x;
    int tid = threadIdx.x;
    int wv = tid >> 6;
    int lane = tid & 63;
    int r15 = lane & 15, g = lane >> 4;

    const unsigned long long* km = km_all + (size_t)n * 1024;
    const unsigned long long* vm = vm_all + (size_t)n * 1024;

    unsigned long long qmask = qm_all[(size_t)n * 1024 + qc * 64 + wv * 16 + r15];
    short8v Qf[2];
    #pragma unroll
    for (int ch = 0; ch < 2; ch++)
        Qf[ch] = expand8((unsigned)(qmask >> ((ch * 4 + g) * 8)) & 0xFFu);

    f32x4 cx[4];
    #pragma unroll
    for (int mt = 0; mt < 4; mt++) cx[mt] = (f32x4){0.f, 0.f, 0.f, 0.f};
    float den = 0.f;

    if (tid < 128) vmbuf[0][tid] = vm[tid];
    __syncthreads();

    for (int kt = 0; kt < 8; kt++) {
        {
            int s = tid >> 1, half = tid & 1;
            unsigned long long m = km[kt * 128 + s];
            #pragma unroll
            for (int j = 0; j < 4; j++) {
                unsigned byte = (unsigned)(m >> (half * 32 + j * 8)) & 0xFFu;
                *reinterpret_cast<short8v*>(&Klds[s][(half * 4 + j) * 8]) = expand8(byte);
            }
        }
        {
            int dh = tid & 63;
            int sc4 = tid >> 6;
            #pragma unroll
            for (int j = 0; j < 4; j++) {
                short8v v2;
                #pragma unroll
                for (int e = 0; e < 8; e++) {
                    unsigned long long mv = vmbuf[kt & 1][sc4 * 32 + j * 8 + e];
                    v2[e] = (short)(((mv >> dh) & 1ull) ? 0x3F80 : 0);
                }
                *reinterpret_cast<short8v*>(&Vt[dh][(sc4 * 4 + j) * 8]) = v2;
            }
        }
        __syncthreads();

        if (tid < 128 && kt + 1 < 8) vmbuf[(kt + 1) & 1][tid] = vm[(kt + 1) * 128 + tid];

        f32x4 pf[8];
        #pragma unroll
        for (int mt = 0; mt < 8; mt++) {
            f32x4 c = (f32x4){0.f, 0.f, 0.f, 0.f};
            #pragma unroll
            for (int ch = 0; ch < 2; ch++) {
                short8v a = *reinterpret_cast<const short8v*>(&Klds[mt * 16 + r15][(ch * 4 + g) * 8]);
                c = __builtin_amdgcn_mfma_f32_16x16x32_bf16(a, Qf[ch], c, 0, 0, 0);
            }
            f32x4 p;
            #pragma unroll
            for (int i = 0; i < 4; i++) {
                p[i] = exp2f(c[i] * ATT_C1 - ATT_C2);
                den += p[i];
            }
            pf[mt] = p;
        }

        int src0 = ((g & 1) << 1) * 16 + r15;
        int src1 = src0 + 16;
        bool hi = (g >= 2);
        #pragma unroll
        for (int c4 = 0; c4 < 4; c4++) {
            unsigned d0 = bfpk(pf[2 * c4][0], pf[2 * c4][1]);
            unsigned d1 = bfpk(pf[2 * c4][2], pf[2 * c4][3]);
            unsigned d2 = bfpk(pf[2 * c4 + 1][0], pf[2 * c4 + 1][1]);
            unsigned d3 = bfpk(pf[2 * c4 + 1][2], pf[2 * c4 + 1][3]);
            unsigned a0 = __shfl((int)d0, src0), b0 = __shfl((int)d2, src0);
            unsigned a1 = __shfl((int)d1, src0), b1 = __shfl((int)d3, src0);
            unsigned a2 = __shfl((int)d0, src1), b2 = __shfl((int)d2, src1);
            unsigned a3 = __shfl((int)d1, src1), b3 = __shfl((int)d3, src1);
            union { unsigned u[4]; short8v s; } bw;
            bw.u[0] = hi ? b0 : a0;
            bw.u[1] = hi ? b1 : a1;
            bw.u[2] = hi ? b2 : a2;
            bw.u[3] = hi ? b3 : a3;
            #pragma unroll
            for (int mt = 0; mt < 4; mt++) {
                short8v a = *reinterpret_cast<const short8v*>(&Vt[mt * 16 + r15][(c4 * 4 + g) * 8]);
                cx[mt] = __builtin_amdgcn_mfma_f32_16x16x32_bf16(a, bw.s, cx[mt], 0, 0, 0);
            }
        }
        __syncthreads();
    }

    den += __shfl_xor(den, 16);
    den += __shfl_xor(den, 32);
    float inv = 1.f / den;

    int b = n >> 4, h = n & 15;
    int row = b * 1024 + qc * 64 + wv * 16 + r15;
    unsigned short* oph = ctxh + (size_t)row * 1024 + h * 64;
    unsigned short* opl = ctxl + (size_t)row * 1024 + h * 64;
    #pragma unroll
    for (int mt = 0; mt < 4; mt++)
        #pragma unroll
        for (int i = 0; i < 4; i++) {
            unsigned short hh, ll;
            bsplit(cx[mt][i] * inv, hh, ll);
            oph[mt * 16 + g * 4 + i] = hh;
            opl[mt * 16 + g * 4 + i] = ll;
        }
}

// ---------------------------------------------------------------------------
extern "C" void kernel_launch(void* const* d_in, const int* in_sizes, int n_in,
                              void* d_out, int out_size, void* d_ws, size_t ws_size,
                              hipStream_t stream) {
    const float* x    = (const float*)d_in[0];
    const float* Wq   = (const float*)d_in[1];
    const float* Wk   = (const float*)d_in[2];
    const float* Wv   = (const float*)d_in[3];
    const float* Wo   = (const float*)d_in[4];
    const float* bo   = (const float*)d_in[5];
    const float* Wqi  = (const float*)d_in[6];
    const float* Wqr  = (const float*)d_in[7];
    const float* Wki  = (const float*)d_in[8];
    const float* Wkr  = (const float*)d_in[9];
    const float* Wvi  = (const float*)d_in[10];
    const float* Wvr  = (const float*)d_in[11];
    const float* thq  = (const float*)d_in[12];
    const float* thk  = (const float*)d_in[13];
    const float* thv  = (const float*)d_in[14];

    char* ws = (char*)d_ws;
    float* cur = (float*)(ws + WS_CUR);
    unsigned short* xh  = (unsigned short*)(ws + WS_XH);
    unsigned short* xl  = (unsigned short*)(ws + WS_XL);
    unsigned short* wch = (unsigned short*)(ws + WS_WCH);
    unsigned short* wcl = (unsigned short*)(ws + WS_WCL);
    unsigned long long* masks = (unsigned long long*)(ws + WS_MSK);
    unsigned short* ctxh = (unsigned short*)(ws + WS_CTXH);
    unsigned short* ctxl = (unsigned short*)(ws + WS_CTXL);
    unsigned short* woh = (unsigned short*)(ws + WS_WOH);
    unsigned short* wol = (unsigned short*)(ws + WS_WOL);
    float* outp = (float*)d_out;

    k_split_x<<<dim3(4096, 1, 1), 256, 0, stream>>>(x, xh, xl);
    k_wc_split<<<dim3(1024, 3, 1), 256, 0, stream>>>(Wq, Wk, Wv, Wqi, Wki, Wvi, wch, wcl);
    k_mfma_gemm<0><<<dim3(32, 8, 3), 512, 0, stream>>>(xh, xl, wch, wcl, cur, nullptr);
    k_split_wo<<<dim3(1024, 1, 1), 256, 0, stream>>>(Wo, woh, wol);
    k_lif<<<dim3(192, 1, 1), 64, 0, stream>>>(cur, Wqr, Wkr, Wvr, thq, thk, thv, masks);
    k_attn_mfma<<<dim3(16, 64, 1), 256, 0, stream>>>(masks, ctxh, ctxl);
    k_mfma_gemm<1><<<dim3(32, 8, 1), 512, 0, stream>>>(ctxh, ctxl, woh, wol, outp, bo);
}